// Round 11
// baseline (8075.114 us; speedup 1.0000x reference)
//
#include <hip/hip_runtime.h>

// N=512 batch, T=256, H=512, D=9. 257 encode + 256 decode steps, LSTM + fc(sigmoid).
// Persistent kernel, 16 clusters x 32 wgs x 256 threads. cl = ((wg&7)<<1)|(wg>>8): the two
// clusters of one XCD interleave on its CUs -> co-resident wgs come from DIFFERENT clusters
// (independent step cadence = latency overlap). W rows packed unit-major x gate so each lane's
// MFMA acc holds all 4 gates of one unit -> LSTM cell entirely in registers (c in VGPRs).
// 1-phase 64KB LDS staging: one vmcnt(0), 3 barriers/step. bf16 hi/lo 3-term MFMA (exact).

#define TT 256
#define HH 512
#define DD 9
#define TP1 257
#define NSTEP 513
#define THREADS 256
#define NWG 512
#define NCL 16
#define WPC 32

// ws byte offsets
#define WF_HI_B 0u          // Wfrag hi: [wl32][rb4][kt16][lane64][i8] bf16 = 2 MB
#define WF_LO_B 2097152u    // Wfrag lo: 2 MB
#define HFRAG_B 4194304u    // hfrag: [par2][cl16] x 65536 B ([kt16][arr2][g4][col32][i8] bf16)
#define HROW_B  6291456u    // hrow:  [par2][cl16] x 65536 B ([col32][k512] f32)
#define U32_B   8388608u    // flags[512] | ctr @+3072 | xcc @+4096

// LDS float offsets (17556 floats = 68.6 KB; x2 wgs = 137 KB < 160)
#define L_ST    0           // staging: 16 kt x 4096 B = 16384 floats
#define L_HNEW  16384       // hnew[u16][33]
#define L_WIH   16912       // wih[u16][40] (gt*9+d packed, pad to 40)
#define L_MISC  17552
#define L_TOT   17556

typedef short s8v __attribute__((ext_vector_type(8)));
typedef float f4v __attribute__((ext_vector_type(4)));
typedef int   i4v __attribute__((ext_vector_type(4)));

__device__ __forceinline__ float sigmoidf_(float v){ return 1.0f/(1.0f+__expf(-v)); }
__device__ __forceinline__ float tanhf_(float v){ return 1.0f - 2.0f/(__expf(2.0f*v)+1.0f); }
__device__ __forceinline__ unsigned short bf16hi_rne(float f){
    unsigned u = __float_as_uint(f);
    return (unsigned short)((u + 0x7fffu + ((u>>16)&1u)) >> 16);
}

__device__ __forceinline__ void ld16i(i4v& d, const char* p){
    asm volatile("global_load_dwordx4 %0, %1, off sc0" : "=v"(d) : "v"(p));
}
__device__ __forceinline__ void ld16f(f4v& d, const char* p){
    asm volatile("global_load_dwordx4 %0, %1, off sc0" : "=v"(d) : "v"(p));
}
__device__ __forceinline__ void wait_vm0_mem(){
    asm volatile("s_waitcnt vmcnt(0)" ::: "memory");
}
__device__ __forceinline__ void wait_vm0_8f(f4v& a0,f4v& a1,f4v& a2,f4v& a3,
                                            f4v& a4,f4v& a5,f4v& a6,f4v& a7){
    asm volatile("s_waitcnt vmcnt(0)"
                 : "+v"(a0),"+v"(a1),"+v"(a2),"+v"(a3),
                   "+v"(a4),"+v"(a5),"+v"(a6),"+v"(a7) :: "memory");
}
__device__ __forceinline__ void lgkm0_bar(){
    asm volatile("s_waitcnt lgkmcnt(0)" ::: "memory");
    __builtin_amdgcn_s_barrier();
}

// init: W_hh -> A-fragments (hi/lo), rows packed unit-major x gate; h0 -> hfrag[0]; zero u32s.
__global__ void rnn_init_kernel(const float* __restrict__ W_hh,
                                const float* __restrict__ h0,
                                char* __restrict__ wsb) {
    int idx = blockIdx.x * blockDim.x + threadIdx.x;   // 0 .. 1048575
    {
        int i  = idx & 7;
        int l  = (idx >> 3) & 63;
        int kt = (idx >> 9) & 15;
        int rb = (idx >> 13) & 3;
        int wl = idx >> 15;
        int m = l & 15, g = l >> 4;
        int gt = m & 3, lu = m >> 2;                 // tile row = unit*4 + gate
        int grow = gt * 512 + wl * 16 + rb * 4 + lu;
        int k = kt * 32 + g * 8 + i;
        float v = W_hh[grow * 512 + k];
        unsigned short hi = bf16hi_rne(v);
        float fh = __uint_as_float(((unsigned)hi) << 16);
        unsigned short lo = bf16hi_rne(v - fh);
        ((unsigned short*)(wsb + WF_HI_B))[idx] = hi;
        ((unsigned short*)(wsb + WF_LO_B))[idx] = lo;
    }
    if (idx < 524288) {   // hfrag par 0: [cl16][kt16][arr2][g4][col32][i8]
        int i   = idx & 7;
        int arr = (idx >> 10) & 1;
        int kt  = (idx >> 11) & 15;
        int cl  = idx >> 15;
        int rem = idx & 32767;
        int j = kt * 32 + ((idx >> 8) & 3) * 8 + i;
        float v = h0[j];
        unsigned short hi = bf16hi_rne(v);
        unsigned short w = hi;
        if (arr) {
            float fh = __uint_as_float(((unsigned)hi) << 16);
            w = bf16hi_rne(v - fh);
        }
        ((unsigned short*)(wsb + HFRAG_B + (unsigned)cl * 65536u))[rem] = w;
    }
    if (idx < 2048) ((unsigned int*)(wsb + U32_B))[idx] = 0u;
}

__global__ __launch_bounds__(THREADS, 2)
void rnn_persist_kernel(const float* __restrict__ x,
                        const float* __restrict__ W_ih,
                        const float* __restrict__ b_ih,
                        const float* __restrict__ b_hh,
                        const float* __restrict__ fc_W,
                        const float* __restrict__ fc_b,
                        const float* __restrict__ c0,
                        char* __restrict__ wsb,
                        float* __restrict__ out) {
    __shared__ float smem[L_TOT];
    char* ldsst = (char*)smem;          // staging at byte 0 (64 KB)

    const int wg  = blockIdx.x;
    const int cl  = ((wg & 7) << 1) | (wg >> 8);   // 2 clusters per XCD, CU-interleaved
    const int wl  = (wg >> 3) & 31;
    const int j0  = wl * 16;
    const int nb0 = cl * 32;
    const int tid = threadIdx.x;
    const int lane = tid & 63;
    const int rb   = tid >> 6;          // wave id -> unit block rb*4..rb*4+3
    const int m    = lane & 15;         // batch col (and +16)
    const int g    = lane >> 4;         // k-group; also local-unit within wave
    const int gu   = wl * 16 + rb * 4 + g;   // this lane's global hidden unit

    unsigned int* flags = (unsigned int*)(wsb + U32_B);        // [cl*32 + wl]
    unsigned int* ctr   = (unsigned int*)(wsb + U32_B + 3072);
    unsigned int* xccb  = (unsigned int*)(wsb + U32_B + 4096); // [wg]

    // ---- one-time: wih to LDS ----
    for (int i2 = tid; i2 < 16 * 4 * DD; i2 += THREADS) {
        int u = i2 / 36; int r2 = i2 - u * 36; int gt = r2 / 9; int d = r2 - gt * 9;
        smem[L_WIH + u * 40 + gt * 9 + d] = W_ih[(gt * 512 + wl * 16 + u) * DD + d];
    }

    // ---- one-time: per-lane registers: bias (4), c-state (2) ----
    const float bias0 = b_ih[gu]        + b_hh[gu];
    const float bias1 = b_ih[512 + gu]  + b_hh[512 + gu];
    const float bias2 = b_ih[1024 + gu] + b_hh[1024 + gu];
    const float bias3 = b_ih[1536 + gu] + b_hh[1536 + gu];
    float creg0 = c0[gu], creg1 = c0[gu];

    // ---- one-time: W A-fragments into registers (hi + lo) ----
    s8v wAh[16], wAl[16];
    {
        const char* base = wsb + (unsigned)(((wl*4 + rb)*16)*64 + lane)*16u;
#pragma unroll
        for (int kt = 0; kt < 16; ++kt) {
            wAh[kt] = *(const s8v*)(base + WF_HI_B + kt*1024);
            wAl[kt] = *(const s8v*)(base + WF_LO_B + kt*1024);
        }
    }

    // ---- startup: publish XCD id, grid barrier, co-location check ----
    if (tid == 0) {
        unsigned xcc;
        asm volatile("s_getreg_b32 %0, hwreg(HW_REG_XCC_ID, 0, 32)" : "=s"(xcc));
        __hip_atomic_store(xccb + wg, xcc + 1u, __ATOMIC_RELAXED, __HIP_MEMORY_SCOPE_AGENT);
        __hip_atomic_fetch_add(ctr, 1u, __ATOMIC_RELEASE, __HIP_MEMORY_SCOPE_AGENT);
        while (__hip_atomic_load(ctr, __ATOMIC_RELAXED, __HIP_MEMORY_SCOPE_AGENT) < NWG)
            __builtin_amdgcn_s_sleep(8);
    }
    __syncthreads();
    {
        unsigned v = 0;
        if (tid < WPC) {
            int member = (cl >> 1) + 256 * (cl & 1) + 8 * tid;   // wgs of this cluster
            v = __hip_atomic_load(xccb + member, __ATOMIC_RELAXED,
                                  __HIP_MEMORY_SCOPE_AGENT);
        }
        unsigned v0 = __shfl(v, 0, 64);
        bool ok = (tid >= WPC) || (v != 0u && v == v0);
        unsigned long long mk = __ballot(ok);
        if (tid == 0) smem[L_MISC] = (mk == ~0ull) ? 1.0f : 0.0f;
    }
    __syncthreads();
    const bool fast = (smem[L_MISC] != 0.0f);

    const int fg = tid >> 4, fl = tid & 15;
    const int fgc = (fg < DD) ? fg : 0;

    for (int s = 0; s < NSTEP; ++s) {
        const int par = s & 1;
        const char* hsrc = wsb + HFRAG_B + (unsigned)(par*16 + cl) * 65536u;
        unsigned int* flg = flags + cl * 32;
        const bool dec = (s >= TP1 + 1);
        const bool enc = (s < TP1);

        // ---- A. step wait: per-lane atomic poll (coherence-point read) ----
        if (s > 0) {
            if (tid < WPC) {
                for (;;) {
                    unsigned v = __hip_atomic_load(flg + tid, __ATOMIC_RELAXED,
                                                   __HIP_MEMORY_SCOPE_AGENT);
                    if (__all((int)(v >= (unsigned)s))) break;
                    __builtin_amdgcn_s_sleep(2);
                }
            }
            __syncthreads();
            if (fast) __builtin_amdgcn_fence(__ATOMIC_ACQUIRE, "workgroup");
            else      __builtin_amdgcn_fence(__ATOMIC_ACQUIRE, "agent");
        }

        // ---- B. issue ALL 16 hfrag loads ----
        i4v hb[16];
#pragma unroll
        for (int c = 0; c < 16; ++c)
            ld16i(hb[c], hsrc + c*4096 + tid*16);

        // ---- C. x loads for this lane's two batches (encode) ----
        float xv0[DD], xv1[DD];
        if (enc) {
            const float* xp0 = x + (size_t)(nb0 + m) * (TP1 * DD) + s * DD;
            const float* xp1 = x + (size_t)(nb0 + m + 16) * (TP1 * DD) + s * DD;
#pragma unroll
            for (int d = 0; d < DD; ++d) { xv0[d] = xp0[d]; xv1[d] = xp1[d]; }
        }

        // ---- D. one vm stall; stage all 16 kt into 64 KB LDS ----
        wait_vm0_mem();
#pragma unroll
        for (int c = 0; c < 16; ++c)
            *(i4v*)(ldsst + c*4096 + tid*16) = hb[c];

        // ---- E. fc hrow loads (decode) — in flight through the GEMM ----
        f4v q0,q1,q2,q3,q4,q5,q6,q7;
        if (dec) {
            const char* hp = wsb + HROW_B + (unsigned)(par*16 + cl)*65536u
                             + (unsigned)(wl*512 + fl*32)*4u;
            ld16f(q0, hp);      ld16f(q1, hp+16);  ld16f(q2, hp+32);  ld16f(q3, hp+48);
            ld16f(q4, hp+64);   ld16f(q5, hp+80);  ld16f(q6, hp+96);  ld16f(q7, hp+112);
        }
        lgkm0_bar();

        // ---- F. GEMM: 16 kt, 6 MFMA each (hi*hi, lo*hi, hi*lo) ----
        f4v acc0 = {0.f,0.f,0.f,0.f}, acc1 = {0.f,0.f,0.f,0.f};
#pragma unroll
        for (int kt = 0; kt < 16; ++kt) {
            const char* bb = ldsst + kt*4096;
            s8v bh0 = *(const s8v*)(bb + g*512        + m*16);
            s8v bh1 = *(const s8v*)(bb + g*512        + m*16 + 256);
            s8v bl0 = *(const s8v*)(bb + 2048 + g*512 + m*16);
            s8v bl1 = *(const s8v*)(bb + 2048 + g*512 + m*16 + 256);
            acc0 = __builtin_amdgcn_mfma_f32_16x16x32_bf16(wAh[kt], bh0, acc0, 0,0,0);
            acc1 = __builtin_amdgcn_mfma_f32_16x16x32_bf16(wAh[kt], bh1, acc1, 0,0,0);
            acc0 = __builtin_amdgcn_mfma_f32_16x16x32_bf16(wAl[kt], bh0, acc0, 0,0,0);
            acc1 = __builtin_amdgcn_mfma_f32_16x16x32_bf16(wAl[kt], bh1, acc1, 0,0,0);
            acc0 = __builtin_amdgcn_mfma_f32_16x16x32_bf16(wAh[kt], bl0, acc0, 0,0,0);
            acc1 = __builtin_amdgcn_mfma_f32_16x16x32_bf16(wAh[kt], bl1, acc1, 0,0,0);
        }

        // ---- G. LSTM cell IN REGISTERS: lane owns unit gu, batches m / m+16 ----
        {
            float wv[36];
            if (enc) {
                const float* wb2 = smem + L_WIH + (rb*4 + g) * 40;
#pragma unroll
                for (int r2 = 0; r2 < 9; ++r2)
                    *(f4v*)(wv + r2*4) = *(const f4v*)(wb2 + r2*4);
            }
            // half 0: batch col m
            {
                float vi = acc0.x + bias0, vf = acc0.y + bias1;
                float vg = acc0.z + bias2, vo = acc0.w + bias3;
                if (enc) {
#pragma unroll
                    for (int d = 0; d < DD; ++d) {
                        vi += xv0[d] * wv[d];      vf += xv0[d] * wv[9 + d];
                        vg += xv0[d] * wv[18 + d]; vo += xv0[d] * wv[27 + d];
                    }
                }
                float cn = sigmoidf_(vf) * creg0 + sigmoidf_(vi) * tanhf_(vg);
                creg0 = cn;
                smem[L_HNEW + (rb*4 + g) * 33 + m] = sigmoidf_(vo) * tanhf_(cn);
            }
            // half 1: batch col m+16
            {
                float vi = acc1.x + bias0, vf = acc1.y + bias1;
                float vg = acc1.z + bias2, vo = acc1.w + bias3;
                if (enc) {
#pragma unroll
                    for (int d = 0; d < DD; ++d) {
                        vi += xv1[d] * wv[d];      vf += xv1[d] * wv[9 + d];
                        vg += xv1[d] * wv[18 + d]; vo += xv1[d] * wv[27 + d];
                    }
                }
                float cn = sigmoidf_(vf) * creg1 + sigmoidf_(vi) * tanhf_(vg);
                creg1 = cn;
                smem[L_HNEW + (rb*4 + g) * 33 + m + 16] = sigmoidf_(vo) * tanhf_(cn);
            }
        }
        lgkm0_bar();

        // ---- H. hrow write + pack hfrag for next step (from hnew) ----
        {
            float* hrp = (float*)(wsb + HROW_B + (unsigned)((par^1)*16 + cl)*65536u);
            const int kl = tid & 15, nl0 = tid >> 4;
#pragma unroll
            for (int i = 0; i < 2; ++i) {
                const int nl = nl0 + i * 16;
                hrp[nl * 512 + j0 + kl] = smem[L_HNEW + kl * 33 + nl];
            }
        }
        if (tid < 128) {
            const int col = tid & 31, jblk = (tid >> 5) & 1, arr = (tid >> 6) & 1;
            const int jb = wl * 2 + jblk;
            const int kt = jb >> 2, gg = jb & 3;
            s8v v;
#pragma unroll
            for (int i = 0; i < 8; ++i) {
                float f = smem[L_HNEW + (jblk * 8 + i) * 33 + col];
                unsigned short hi = bf16hi_rne(f);
                unsigned short w = hi;
                if (arr) {
                    float fh = __uint_as_float(((unsigned)hi) << 16);
                    w = bf16hi_rne(f - fh);
                }
                v[i] = (short)w;
            }
            char* dst = wsb + HFRAG_B + (unsigned)((par^1)*16 + cl)*65536u
                        + (unsigned)(kt*4096 + arr*2048 + gg*512 + col*16);
            *(s8v*)dst = v;
        }
        wait_vm0_mem();   // drains hrow/pack stores (and q loads)
        __syncthreads();

        // ---- I. signal ----
        if (tid == 0) {
            if (fast) {
                __hip_atomic_store(flg + wl, (unsigned)(s + 1),
                                   __ATOMIC_RELAXED, __HIP_MEMORY_SCOPE_AGENT);
            } else {
                __builtin_amdgcn_fence(__ATOMIC_RELEASE, "agent");
                __hip_atomic_store(flg + wl, (unsigned)(s + 1),
                                   __ATOMIC_RELEASE, __HIP_MEMORY_SCOPE_AGENT);
            }
        }

        // ---- J. fc compute for h(s) (decode): out[:, s-258, :] ----
        if (dec && fg < DD) {
            const f4v* wv = (const f4v*)(fc_W + fgc * HH + fl * 32);
            wait_vm0_8f(q0,q1,q2,q3,q4,q5,q6,q7);
            float acc = 0.f;
            acc += q0.x*wv[0].x + q0.y*wv[0].y + q0.z*wv[0].z + q0.w*wv[0].w;
            acc += q1.x*wv[1].x + q1.y*wv[1].y + q1.z*wv[1].z + q1.w*wv[1].w;
            acc += q2.x*wv[2].x + q2.y*wv[2].y + q2.z*wv[2].z + q2.w*wv[2].w;
            acc += q3.x*wv[3].x + q3.y*wv[3].y + q3.z*wv[3].z + q3.w*wv[3].w;
            acc += q4.x*wv[4].x + q4.y*wv[4].y + q4.z*wv[4].z + q4.w*wv[4].w;
            acc += q5.x*wv[5].x + q5.y*wv[5].y + q5.z*wv[5].z + q5.w*wv[5].w;
            acc += q6.x*wv[6].x + q6.y*wv[6].y + q6.z*wv[6].z + q6.w*wv[6].w;
            acc += q7.x*wv[7].x + q7.y*wv[7].y + q7.z*wv[7].z + q7.w*wv[7].w;
            acc += __shfl_down(acc, 8, 16);
            acc += __shfl_down(acc, 4, 16);
            acc += __shfl_down(acc, 2, 16);
            acc += __shfl_down(acc, 1, 16);
            if (fl == 0)
                out[(size_t)(nb0 + wl) * (TT * DD) + (s - (TP1 + 1)) * DD + fgc] =
                    1.0f / (1.0f + __expf(-(acc + fc_b[fgc])));
        }
    }

    // ---- tail fc: td = 255 from h(513) ----
    {
        if (tid < WPC) {
            for (;;) {
                unsigned v = __hip_atomic_load(flags + cl * 32 + tid,
                                               __ATOMIC_RELAXED, __HIP_MEMORY_SCOPE_AGENT);
                if (__all((int)(v >= (unsigned)NSTEP))) break;
                __builtin_amdgcn_s_sleep(2);
            }
        }
        __syncthreads();
        if (fast) __builtin_amdgcn_fence(__ATOMIC_ACQUIRE, "workgroup");
        else      __builtin_amdgcn_fence(__ATOMIC_ACQUIRE, "agent");

        if (fg < DD) {
            const char* hp = wsb + HROW_B + (unsigned)((NSTEP & 1)*16 + cl)*65536u
                             + (unsigned)(wl*512 + fl*32)*4u;
            f4v q0,q1,q2,q3,q4,q5,q6,q7;
            ld16f(q0, hp);      ld16f(q1, hp+16);  ld16f(q2, hp+32);  ld16f(q3, hp+48);
            ld16f(q4, hp+64);   ld16f(q5, hp+80);  ld16f(q6, hp+96);  ld16f(q7, hp+112);
            const f4v* wv = (const f4v*)(fc_W + fgc * HH + fl * 32);
            wait_vm0_8f(q0,q1,q2,q3,q4,q5,q6,q7);
            float acc = 0.f;
            acc += q0.x*wv[0].x + q0.y*wv[0].y + q0.z*wv[0].z + q0.w*wv[0].w;
            acc += q1.x*wv[1].x + q1.y*wv[1].y + q1.z*wv[1].z + q1.w*wv[1].w;
            acc += q2.x*wv[2].x + q2.y*wv[2].y + q2.z*wv[2].z + q2.w*wv[2].w;
            acc += q3.x*wv[3].x + q3.y*wv[3].y + q3.z*wv[3].z + q3.w*wv[3].w;
            acc += q4.x*wv[4].x + q4.y*wv[4].y + q4.z*wv[4].z + q4.w*wv[4].w;
            acc += q5.x*wv[5].x + q5.y*wv[5].y + q5.z*wv[5].z + q5.w*wv[5].w;
            acc += q6.x*wv[6].x + q6.y*wv[6].y + q6.z*wv[6].z + q6.w*wv[6].w;
            acc += q7.x*wv[7].x + q7.y*wv[7].y + q7.z*wv[7].z + q7.w*wv[7].w;
            acc += __shfl_down(acc, 8, 16);
            acc += __shfl_down(acc, 4, 16);
            acc += __shfl_down(acc, 2, 16);
            acc += __shfl_down(acc, 1, 16);
            if (fl == 0)
                out[(size_t)(nb0 + wl) * (TT * DD) + 255 * DD + fgc] =
                    1.0f / (1.0f + __expf(-(acc + fc_b[fgc])));
        }
    }
}

extern "C" void kernel_launch(void* const* d_in, const int* in_sizes, int n_in,
                              void* d_out, int out_size, void* d_ws, size_t ws_size,
                              hipStream_t stream) {
    (void)in_sizes; (void)n_in; (void)out_size; (void)ws_size;
    const float* x    = (const float*)d_in[0];
    const float* W_ih = (const float*)d_in[1];
    const float* W_hh = (const float*)d_in[2];
    const float* b_ih = (const float*)d_in[3];
    const float* b_hh = (const float*)d_in[4];
    const float* fc_W = (const float*)d_in[5];
    const float* fc_b = (const float*)d_in[6];
    const float* h0   = (const float*)d_in[7];
    const float* c0   = (const float*)d_in[8];
    float* out = (float*)d_out;
    char*  wsb = (char*)d_ws;

    hipLaunchKernelGGL(rnn_init_kernel, dim3(4096), dim3(256), 0, stream,
                       W_hh, h0, wsb);
    hipLaunchKernelGGL(rnn_persist_kernel, dim3(NWG), dim3(THREADS), 0, stream,
                       x, W_ih, b_ih, b_hh, fc_W, fc_b, c0, wsb, out);
}

// Round 12
// 7132.864 us; speedup vs baseline: 1.1321x; 1.1321x over previous
//
#include <hip/hip_runtime.h>

// N=512 batch, T=256, H=512, D=9. 257 encode + 256 decode steps, LSTM + fc(sigmoid).
// Persistent kernel, 16 clusters x 32 wgs x 256 threads (R10 placement: cl = wg&15).
// W rows packed unit-major x gate so each lane's MFMA acc holds all 4 gates of one unit ->
// LSTM cell entirely in registers (c in VGPRs, bias in VGPRs, gates never in LDS).
// bf16 hi/lo 3-term MFMA (exact). 2-phase 32KB staging, one vmcnt(0)/step, atomic flag polls.

#define TT 256
#define HH 512
#define DD 9
#define TP1 257
#define NSTEP 513
#define THREADS 256
#define NWG 512
#define NCL 16
#define WPC 32

// ws byte offsets
#define WF_HI_B 0u          // Wfrag hi: [wl32][rb4][kt16][lane64][i8] bf16 = 2 MB
#define WF_LO_B 2097152u    // Wfrag lo: 2 MB
#define HFRAG_B 4194304u    // hfrag: [par2][cl16] x 65536 B ([kt16][arr2][g4][col32][i8] bf16)
#define HROW_B  6291456u    // hrow:  [par2][cl16] x 65536 B ([col32][k512] f32)
#define U32_B   8388608u    // flags[512] | ctr @+3072 | xcc @+4096

// LDS float offsets (9364 floats = 36.6 KB; x2 wgs = 73 KB)
#define L_ST    0           // staging: 8 kt x 4096 B = 8192 floats (reused A/B phase)
#define L_HNEW  8192        // hnew[u16][33]
#define L_WIH   8720        // wih[u16][40]
#define L_MISC  9360
#define L_TOT   9364

typedef short s8v __attribute__((ext_vector_type(8)));
typedef float f4v __attribute__((ext_vector_type(4)));
typedef int   i4v __attribute__((ext_vector_type(4)));

__device__ __forceinline__ float sigmoidf_(float v){ return 1.0f/(1.0f+__expf(-v)); }
__device__ __forceinline__ float tanhf_(float v){ return 1.0f - 2.0f/(__expf(2.0f*v)+1.0f); }
__device__ __forceinline__ unsigned short bf16hi_rne(float f){
    unsigned u = __float_as_uint(f);
    return (unsigned short)((u + 0x7fffu + ((u>>16)&1u)) >> 16);
}

__device__ __forceinline__ void ld16i(i4v& d, const char* p){
    asm volatile("global_load_dwordx4 %0, %1, off sc0" : "=v"(d) : "v"(p));
}
__device__ __forceinline__ void ld16f(f4v& d, const char* p){
    asm volatile("global_load_dwordx4 %0, %1, off sc0" : "=v"(d) : "v"(p));
}
__device__ __forceinline__ void wait_vm0_mem(){
    asm volatile("s_waitcnt vmcnt(0)" ::: "memory");
}
__device__ __forceinline__ void wait_vm0_8f(f4v& a0,f4v& a1,f4v& a2,f4v& a3,
                                            f4v& a4,f4v& a5,f4v& a6,f4v& a7){
    asm volatile("s_waitcnt vmcnt(0)"
                 : "+v"(a0),"+v"(a1),"+v"(a2),"+v"(a3),
                   "+v"(a4),"+v"(a5),"+v"(a6),"+v"(a7) :: "memory");
}
__device__ __forceinline__ void lgkm0_bar(){
    asm volatile("s_waitcnt lgkmcnt(0)" ::: "memory");
    __builtin_amdgcn_s_barrier();
}

// init: W_hh -> A-fragments (hi/lo), tile row = unit*4 + gate; h0 -> hfrag[0]; zero u32s.
__global__ void rnn_init_kernel(const float* __restrict__ W_hh,
                                const float* __restrict__ h0,
                                char* __restrict__ wsb) {
    int idx = blockIdx.x * blockDim.x + threadIdx.x;   // 0 .. 1048575
    {
        int i  = idx & 7;
        int l  = (idx >> 3) & 63;
        int kt = (idx >> 9) & 15;
        int rb = (idx >> 13) & 3;
        int wl = idx >> 15;
        int m = l & 15, g = l >> 4;
        int gt = m & 3, lu = m >> 2;                 // tile row m = lu*4 + gt
        int grow = gt * 512 + wl * 16 + rb * 4 + lu;
        int k = kt * 32 + g * 8 + i;
        float v = W_hh[grow * 512 + k];
        unsigned short hi = bf16hi_rne(v);
        float fh = __uint_as_float(((unsigned)hi) << 16);
        unsigned short lo = bf16hi_rne(v - fh);
        ((unsigned short*)(wsb + WF_HI_B))[idx] = hi;
        ((unsigned short*)(wsb + WF_LO_B))[idx] = lo;
    }
    if (idx < 524288) {   // hfrag par 0: [cl16][kt16][arr2][g4][col32][i8]
        int i   = idx & 7;
        int arr = (idx >> 10) & 1;
        int kt  = (idx >> 11) & 15;
        int cl  = idx >> 15;
        int rem = idx & 32767;
        int j = kt * 32 + ((idx >> 8) & 3) * 8 + i;
        float v = h0[j];
        unsigned short hi = bf16hi_rne(v);
        unsigned short w = hi;
        if (arr) {
            float fh = __uint_as_float(((unsigned)hi) << 16);
            w = bf16hi_rne(v - fh);
        }
        ((unsigned short*)(wsb + HFRAG_B + (unsigned)cl * 65536u))[rem] = w;
    }
    if (idx < 2048) ((unsigned int*)(wsb + U32_B))[idx] = 0u;
}

__global__ __launch_bounds__(THREADS, 2)
void rnn_persist_kernel(const float* __restrict__ x,
                        const float* __restrict__ W_ih,
                        const float* __restrict__ b_ih,
                        const float* __restrict__ b_hh,
                        const float* __restrict__ fc_W,
                        const float* __restrict__ fc_b,
                        const float* __restrict__ c0,
                        char* __restrict__ wsb,
                        float* __restrict__ out) {
    __shared__ float smem[L_TOT];
    char* ldsst = (char*)smem;          // staging at byte 0 (32 KB)

    const int wg  = blockIdx.x;
    const int cl  = wg & 15;            // R10 placement: cluster -> XCD cl&7
    const int wl  = wg >> 4;            // 0..31
    const int j0  = wl * 16;
    const int nb0 = cl * 32;
    const int tid = threadIdx.x;
    const int lane = tid & 63;
    const int rb   = tid >> 6;          // wave id -> unit block rb*4..rb*4+3
    const int m    = lane & 15;         // batch col (and +16)
    const int g    = lane >> 4;         // k-group; also local-unit within wave
    const int gu   = wl * 16 + rb * 4 + g;   // this lane's global hidden unit

    unsigned int* flags = (unsigned int*)(wsb + U32_B);        // [cl*32 + wl]
    unsigned int* ctr   = (unsigned int*)(wsb + U32_B + 3072);
    unsigned int* xccb  = (unsigned int*)(wsb + U32_B + 4096); // [wg]

    // ---- one-time: wih to LDS ----
    for (int i2 = tid; i2 < 16 * 4 * DD; i2 += THREADS) {
        int u = i2 / 36; int r2 = i2 - u * 36; int gt = r2 / 9; int d = r2 - gt * 9;
        smem[L_WIH + u * 40 + gt * 9 + d] = W_ih[(gt * 512 + wl * 16 + u) * DD + d];
    }

    // ---- one-time: per-lane registers: bias (4), c-state (2) ----
    const float bias0 = b_ih[gu]        + b_hh[gu];
    const float bias1 = b_ih[512 + gu]  + b_hh[512 + gu];
    const float bias2 = b_ih[1024 + gu] + b_hh[1024 + gu];
    const float bias3 = b_ih[1536 + gu] + b_hh[1536 + gu];
    float creg0 = c0[gu], creg1 = c0[gu];

    // ---- one-time: W A-fragments into registers (hi + lo) ----
    s8v wAh[16], wAl[16];
    {
        const char* base = wsb + (unsigned)(((wl*4 + rb)*16)*64 + lane)*16u;
#pragma unroll
        for (int kt = 0; kt < 16; ++kt) {
            wAh[kt] = *(const s8v*)(base + WF_HI_B + kt*1024);
            wAl[kt] = *(const s8v*)(base + WF_LO_B + kt*1024);
        }
    }

    // ---- startup: publish XCD id, grid barrier, co-location check (R10 form) ----
    if (tid == 0) {
        unsigned xcc;
        asm volatile("s_getreg_b32 %0, hwreg(HW_REG_XCC_ID, 0, 32)" : "=s"(xcc));
        __hip_atomic_store(xccb + wg, xcc + 1u, __ATOMIC_RELAXED, __HIP_MEMORY_SCOPE_AGENT);
        __hip_atomic_fetch_add(ctr, 1u, __ATOMIC_RELEASE, __HIP_MEMORY_SCOPE_AGENT);
        while (__hip_atomic_load(ctr, __ATOMIC_RELAXED, __HIP_MEMORY_SCOPE_AGENT) < NWG)
            __builtin_amdgcn_s_sleep(8);
    }
    __syncthreads();
    {
        unsigned v = (tid < WPC)
            ? __hip_atomic_load(xccb + tid * NCL + cl, __ATOMIC_RELAXED,
                                __HIP_MEMORY_SCOPE_AGENT) : 0u;
        unsigned v0 = __shfl(v, 0, 64);
        bool ok = (tid >= WPC) || (v != 0u && v == v0);
        unsigned long long mk = __ballot(ok);
        if (tid == 0) smem[L_MISC] = (mk == ~0ull) ? 1.0f : 0.0f;
    }
    __syncthreads();
    const bool fast = (smem[L_MISC] != 0.0f);

    const int fg = tid >> 4, fl = tid & 15;
    const int fgc = (fg < DD) ? fg : 0;

    for (int s = 0; s < NSTEP; ++s) {
        const int par = s & 1;
        const char* hsrc = wsb + HFRAG_B + (unsigned)(par*16 + cl) * 65536u;
        unsigned int* flg = flags + cl * 32;
        const bool dec = (s >= TP1 + 1);
        const bool enc = (s < TP1);

        // ---- A. step wait: per-lane atomic poll (coherence-point read) ----
        if (s > 0) {
            if (tid < WPC) {
                for (;;) {
                    unsigned v = __hip_atomic_load(flg + tid, __ATOMIC_RELAXED,
                                                   __HIP_MEMORY_SCOPE_AGENT);
                    if (__all((int)(v >= (unsigned)s))) break;
                    __builtin_amdgcn_s_sleep(2);
                }
            }
            __syncthreads();
            if (fast) __builtin_amdgcn_fence(__ATOMIC_ACQUIRE, "workgroup");
            else      __builtin_amdgcn_fence(__ATOMIC_ACQUIRE, "agent");
        }

        // ---- B. issue ALL 16 hfrag loads (whole step) ----
        i4v hb[16];
#pragma unroll
        for (int c = 0; c < 16; ++c)
            ld16i(hb[c], hsrc + c*4096 + tid*16);

        // ---- C. x loads for this lane's two batches (encode) ----
        float xv0[DD], xv1[DD];
        if (enc) {
            const float* xp0 = x + (size_t)(nb0 + m) * (TP1 * DD) + s * DD;
            const float* xp1 = x + (size_t)(nb0 + m + 16) * (TP1 * DD) + s * DD;
#pragma unroll
            for (int d = 0; d < DD; ++d) { xv0[d] = xp0[d]; xv1[d] = xp1[d]; }
        }

        // ---- D. one vm stall; stage phase A (kt 0-7) ----
        wait_vm0_mem();
#pragma unroll
        for (int c = 0; c < 8; ++c)
            *(i4v*)(ldsst + c*4096 + tid*16) = hb[c];
        lgkm0_bar();

        // ---- E. GEMM phase A: kt 0-7 ----
        f4v acc0 = {0.f,0.f,0.f,0.f}, acc1 = {0.f,0.f,0.f,0.f};
#pragma unroll
        for (int kt = 0; kt < 8; ++kt) {
            const char* bb = ldsst + kt*4096;
            s8v bh0 = *(const s8v*)(bb + g*512        + m*16);
            s8v bh1 = *(const s8v*)(bb + g*512        + m*16 + 256);
            s8v bl0 = *(const s8v*)(bb + 2048 + g*512 + m*16);
            s8v bl1 = *(const s8v*)(bb + 2048 + g*512 + m*16 + 256);
            acc0 = __builtin_amdgcn_mfma_f32_16x16x32_bf16(wAh[kt], bh0, acc0, 0,0,0);
            acc1 = __builtin_amdgcn_mfma_f32_16x16x32_bf16(wAh[kt], bh1, acc1, 0,0,0);
            acc0 = __builtin_amdgcn_mfma_f32_16x16x32_bf16(wAl[kt], bh0, acc0, 0,0,0);
            acc1 = __builtin_amdgcn_mfma_f32_16x16x32_bf16(wAl[kt], bh1, acc1, 0,0,0);
            acc0 = __builtin_amdgcn_mfma_f32_16x16x32_bf16(wAh[kt], bl0, acc0, 0,0,0);
            acc1 = __builtin_amdgcn_mfma_f32_16x16x32_bf16(wAh[kt], bl1, acc1, 0,0,0);
        }
        lgkm0_bar();   // all waves done reading phase A

        // ---- F. stage phase B (kt 8-15) ----
#pragma unroll
        for (int c = 0; c < 8; ++c)
            *(i4v*)(ldsst + c*4096 + tid*16) = hb[c + 8];

        // ---- G. fc hrow loads (decode) — in flight through phase B ----
        f4v q0,q1,q2,q3,q4,q5,q6,q7;
        if (dec) {
            const char* hp = wsb + HROW_B + (unsigned)(par*16 + cl)*65536u
                             + (unsigned)(wl*512 + fl*32)*4u;
            ld16f(q0, hp);      ld16f(q1, hp+16);  ld16f(q2, hp+32);  ld16f(q3, hp+48);
            ld16f(q4, hp+64);   ld16f(q5, hp+80);  ld16f(q6, hp+96);  ld16f(q7, hp+112);
        }
        lgkm0_bar();

        // ---- H. GEMM phase B ----
#pragma unroll
        for (int kt = 8; kt < 16; ++kt) {
            const char* bb = ldsst + (kt-8)*4096;
            s8v bh0 = *(const s8v*)(bb + g*512        + m*16);
            s8v bh1 = *(const s8v*)(bb + g*512        + m*16 + 256);
            s8v bl0 = *(const s8v*)(bb + 2048 + g*512 + m*16);
            s8v bl1 = *(const s8v*)(bb + 2048 + g*512 + m*16 + 256);
            acc0 = __builtin_amdgcn_mfma_f32_16x16x32_bf16(wAh[kt], bh0, acc0, 0,0,0);
            acc1 = __builtin_amdgcn_mfma_f32_16x16x32_bf16(wAh[kt], bh1, acc1, 0,0,0);
            acc0 = __builtin_amdgcn_mfma_f32_16x16x32_bf16(wAl[kt], bh0, acc0, 0,0,0);
            acc1 = __builtin_amdgcn_mfma_f32_16x16x32_bf16(wAl[kt], bh1, acc1, 0,0,0);
            acc0 = __builtin_amdgcn_mfma_f32_16x16x32_bf16(wAh[kt], bl0, acc0, 0,0,0);
            acc1 = __builtin_amdgcn_mfma_f32_16x16x32_bf16(wAh[kt], bl1, acc1, 0,0,0);
        }

        // ---- I. LSTM cell IN REGISTERS: lane owns unit gu, batches m / m+16 ----
        {
            float wv[36];
            if (enc) {
                const float* wb2 = smem + L_WIH + (rb*4 + g) * 40;
#pragma unroll
                for (int r2 = 0; r2 < 9; ++r2)
                    *(f4v*)(wv + r2*4) = *(const f4v*)(wb2 + r2*4);
            }
            {
                float vi = acc0.x + bias0, vf = acc0.y + bias1;
                float vg = acc0.z + bias2, vo = acc0.w + bias3;
                if (enc) {
#pragma unroll
                    for (int d = 0; d < DD; ++d) {
                        vi += xv0[d] * wv[d];      vf += xv0[d] * wv[9 + d];
                        vg += xv0[d] * wv[18 + d]; vo += xv0[d] * wv[27 + d];
                    }
                }
                float cn = sigmoidf_(vf) * creg0 + sigmoidf_(vi) * tanhf_(vg);
                creg0 = cn;
                smem[L_HNEW + (rb*4 + g) * 33 + m] = sigmoidf_(vo) * tanhf_(cn);
            }
            {
                float vi = acc1.x + bias0, vf = acc1.y + bias1;
                float vg = acc1.z + bias2, vo = acc1.w + bias3;
                if (enc) {
#pragma unroll
                    for (int d = 0; d < DD; ++d) {
                        vi += xv1[d] * wv[d];      vf += xv1[d] * wv[9 + d];
                        vg += xv1[d] * wv[18 + d]; vo += xv1[d] * wv[27 + d];
                    }
                }
                float cn = sigmoidf_(vf) * creg1 + sigmoidf_(vi) * tanhf_(vg);
                creg1 = cn;
                smem[L_HNEW + (rb*4 + g) * 33 + m + 16] = sigmoidf_(vo) * tanhf_(cn);
            }
        }
        lgkm0_bar();

        // ---- J. hrow write + pack hfrag for next step (from hnew) ----
        {
            float* hrp = (float*)(wsb + HROW_B + (unsigned)((par^1)*16 + cl)*65536u);
            const int kl = tid & 15, nl0 = tid >> 4;
#pragma unroll
            for (int i = 0; i < 2; ++i) {
                const int nl = nl0 + i * 16;
                hrp[nl * 512 + j0 + kl] = smem[L_HNEW + kl * 33 + nl];
            }
        }
        if (tid < 128) {
            const int col = tid & 31, jblk = (tid >> 5) & 1, arr = (tid >> 6) & 1;
            const int jb = wl * 2 + jblk;
            const int kt = jb >> 2, gg = jb & 3;
            s8v v;
#pragma unroll
            for (int i = 0; i < 8; ++i) {
                float f = smem[L_HNEW + (jblk * 8 + i) * 33 + col];
                unsigned short hi = bf16hi_rne(f);
                unsigned short w = hi;
                if (arr) {
                    float fh = __uint_as_float(((unsigned)hi) << 16);
                    w = bf16hi_rne(f - fh);
                }
                v[i] = (short)w;
            }
            char* dst = wsb + HFRAG_B + (unsigned)((par^1)*16 + cl)*65536u
                        + (unsigned)(kt*4096 + arr*2048 + gg*512 + col*16);
            *(s8v*)dst = v;
        }
        wait_vm0_mem();   // drains hrow/pack stores (and q loads)
        __syncthreads();

        // ---- K. signal ----
        if (tid == 0) {
            if (fast) {
                __hip_atomic_store(flg + wl, (unsigned)(s + 1),
                                   __ATOMIC_RELAXED, __HIP_MEMORY_SCOPE_AGENT);
            } else {
                __builtin_amdgcn_fence(__ATOMIC_RELEASE, "agent");
                __hip_atomic_store(flg + wl, (unsigned)(s + 1),
                                   __ATOMIC_RELEASE, __HIP_MEMORY_SCOPE_AGENT);
            }
        }

        // ---- L. fc compute for h(s) (decode): out[:, s-258, :] ----
        if (dec && fg < DD) {
            const f4v* wv = (const f4v*)(fc_W + fgc * HH + fl * 32);
            float acc = 0.f;
            acc += q0.x*wv[0].x + q0.y*wv[0].y + q0.z*wv[0].z + q0.w*wv[0].w;
            acc += q1.x*wv[1].x + q1.y*wv[1].y + q1.z*wv[1].z + q1.w*wv[1].w;
            acc += q2.x*wv[2].x + q2.y*wv[2].y + q2.z*wv[2].z + q2.w*wv[2].w;
            acc += q3.x*wv[3].x + q3.y*wv[3].y + q3.z*wv[3].z + q3.w*wv[3].w;
            acc += q4.x*wv[4].x + q4.y*wv[4].y + q4.z*wv[4].z + q4.w*wv[4].w;
            acc += q5.x*wv[5].x + q5.y*wv[5].y + q5.z*wv[5].z + q5.w*wv[5].w;
            acc += q6.x*wv[6].x + q6.y*wv[6].y + q6.z*wv[6].z + q6.w*wv[6].w;
            acc += q7.x*wv[7].x + q7.y*wv[7].y + q7.z*wv[7].z + q7.w*wv[7].w;
            acc += __shfl_down(acc, 8, 16);
            acc += __shfl_down(acc, 4, 16);
            acc += __shfl_down(acc, 2, 16);
            acc += __shfl_down(acc, 1, 16);
            if (fl == 0)
                out[(size_t)(nb0 + wl) * (TT * DD) + (s - (TP1 + 1)) * DD + fgc] =
                    1.0f / (1.0f + __expf(-(acc + fc_b[fgc])));
        }
    }

    // ---- tail fc: td = 255 from h(513) ----
    {
        if (tid < WPC) {
            for (;;) {
                unsigned v = __hip_atomic_load(flags + cl * 32 + tid,
                                               __ATOMIC_RELAXED, __HIP_MEMORY_SCOPE_AGENT);
                if (__all((int)(v >= (unsigned)NSTEP))) break;
                __builtin_amdgcn_s_sleep(2);
            }
        }
        __syncthreads();
        if (fast) __builtin_amdgcn_fence(__ATOMIC_ACQUIRE, "workgroup");
        else      __builtin_amdgcn_fence(__ATOMIC_ACQUIRE, "agent");

        if (fg < DD) {
            const char* hp = wsb + HROW_B + (unsigned)((NSTEP & 1)*16 + cl)*65536u
                             + (unsigned)(wl*512 + fl*32)*4u;
            f4v q0,q1,q2,q3,q4,q5,q6,q7;
            ld16f(q0, hp);      ld16f(q1, hp+16);  ld16f(q2, hp+32);  ld16f(q3, hp+48);
            ld16f(q4, hp+64);   ld16f(q5, hp+80);  ld16f(q6, hp+96);  ld16f(q7, hp+112);
            const f4v* wv = (const f4v*)(fc_W + fgc * HH + fl * 32);
            wait_vm0_8f(q0,q1,q2,q3,q4,q5,q6,q7);
            float acc = 0.f;
            acc += q0.x*wv[0].x + q0.y*wv[0].y + q0.z*wv[0].z + q0.w*wv[0].w;
            acc += q1.x*wv[1].x + q1.y*wv[1].y + q1.z*wv[1].z + q1.w*wv[1].w;
            acc += q2.x*wv[2].x + q2.y*wv[2].y + q2.z*wv[2].z + q2.w*wv[2].w;
            acc += q3.x*wv[3].x + q3.y*wv[3].y + q3.z*wv[3].z + q3.w*wv[3].w;
            acc += q4.x*wv[4].x + q4.y*wv[4].y + q4.z*wv[4].z + q4.w*wv[4].w;
            acc += q5.x*wv[5].x + q5.y*wv[5].y + q5.z*wv[5].z + q5.w*wv[5].w;
            acc += q6.x*wv[6].x + q6.y*wv[6].y + q6.z*wv[6].z + q6.w*wv[6].w;
            acc += q7.x*wv[7].x + q7.y*wv[7].y + q7.z*wv[7].z + q7.w*wv[7].w;
            acc += __shfl_down(acc, 8, 16);
            acc += __shfl_down(acc, 4, 16);
            acc += __shfl_down(acc, 2, 16);
            acc += __shfl_down(acc, 1, 16);
            if (fl == 0)
                out[(size_t)(nb0 + wl) * (TT * DD) + 255 * DD + fgc] =
                    1.0f / (1.0f + __expf(-(acc + fc_b[fgc])));
        }
    }
}

extern "C" void kernel_launch(void* const* d_in, const int* in_sizes, int n_in,
                              void* d_out, int out_size, void* d_ws, size_t ws_size,
                              hipStream_t stream) {
    (void)in_sizes; (void)n_in; (void)out_size; (void)ws_size;
    const float* x    = (const float*)d_in[0];
    const float* W_ih = (const float*)d_in[1];
    const float* W_hh = (const float*)d_in[2];
    const float* b_ih = (const float*)d_in[3];
    const float* b_hh = (const float*)d_in[4];
    const float* fc_W = (const float*)d_in[5];
    const float* fc_b = (const float*)d_in[6];
    const float* h0   = (const float*)d_in[7];
    const float* c0   = (const float*)d_in[8];
    float* out = (float*)d_out;
    char*  wsb = (char*)d_ws;

    hipLaunchKernelGGL(rnn_init_kernel, dim3(4096), dim3(256), 0, stream,
                       W_hh, h0, wsb);
    hipLaunchKernelGGL(rnn_persist_kernel, dim3(NWG), dim3(THREADS), 0, stream,
                       x, W_ih, b_ih, b_hh, fc_W, fc_b, c0, wsb, out);
}

// Round 14
// 3314.749 us; speedup vs baseline: 2.4361x; 2.1519x over previous
//
#include <hip/hip_runtime.h>

// N=512 batch, T=256, H=512, D=9. 257 encode + 256 decode steps, LSTM + fc(sigmoid).
// Persistent kernel: 256 wgs x 512 threads (1 wg/CU), 8 clusters x 32 wgs (cl = wg&7 -> one
// XCD). 8 waves = 4 row-tiles x 2 K-halves: each wave holds W frags for K=256 only
// (64 VGPRs, halved) -> no spill; partial accs combined via LDS exchange. In-register LSTM
// cell (c,bias in VGPRs). amdgpu_waves_per_eu(2,2) pins allocator at 2 waves/EU (256-reg cap).
// bf16 hi/lo 3-term MFMA (exact). Whole-step 128KB LDS staging, 2 phases, atomic flag sync.
// R14: fix R13's fc bugs — q-load stride 64B -> 16B (contiguous 32 floats/lane), restore
// operand-tied wait_vm0_8f before fc compute (hipcc hoists reg-only ops past bare waitcnt).

#define TT 256
#define HH 512
#define DD 9
#define TP1 257
#define NSTEP 513
#define THREADS 512
#define NWG 256
#define NCL 8
#define WPC 32

// ws byte offsets
#define WF_HI_B 0u          // Wfrag hi: [wl32][rb4][kt16][lane64][i8] bf16 = 2 MB
#define WF_LO_B 2097152u    // Wfrag lo: 2 MB
#define HFRAG_B 4194304u    // hfrag: [par2][cl8] x 131072 B ([kt16][arr2][g4][col64][i8] bf16)
#define HROW_B  6291456u    // hrow:  [par2][cl8] x 131072 B ([col64][k512] f32)
#define U32_B   8388608u    // flags[256] | ctr @+3072 | xcc @+4096

// LDS float offsets (38564 floats = 150.6 KB; 1 wg/CU)
#define L_ST    0           // staging: 16 kt x 8192 B = 32768 floats
#define L_EX    32768       // acc exchange: 8 slots x 64 lanes x 8 f = 4096 floats
#define L_HNEW  36864       // hnew[u16][65]
#define L_WIH   37920       // wih[u16][40]
#define L_MISC  38560
#define L_TOT   38564

typedef short s8v __attribute__((ext_vector_type(8)));
typedef float f4v __attribute__((ext_vector_type(4)));
typedef int   i4v __attribute__((ext_vector_type(4)));

__device__ __forceinline__ float sigmoidf_(float v){ return 1.0f/(1.0f+__expf(-v)); }
__device__ __forceinline__ float tanhf_(float v){ return 1.0f - 2.0f/(__expf(2.0f*v)+1.0f); }
__device__ __forceinline__ unsigned short bf16hi_rne(float f){
    unsigned u = __float_as_uint(f);
    return (unsigned short)((u + 0x7fffu + ((u>>16)&1u)) >> 16);
}

__device__ __forceinline__ void ld16i(i4v& d, const char* p){
    asm volatile("global_load_dwordx4 %0, %1, off sc0" : "=v"(d) : "v"(p));
}
__device__ __forceinline__ void ld16f(f4v& d, const char* p){
    asm volatile("global_load_dwordx4 %0, %1, off sc0" : "=v"(d) : "v"(p));
}
__device__ __forceinline__ void wait_vm0_mem(){
    asm volatile("s_waitcnt vmcnt(0)" ::: "memory");
}
__device__ __forceinline__ void wait_vm0_8f(f4v& a0,f4v& a1,f4v& a2,f4v& a3,
                                            f4v& a4,f4v& a5,f4v& a6,f4v& a7){
    asm volatile("s_waitcnt vmcnt(0)"
                 : "+v"(a0),"+v"(a1),"+v"(a2),"+v"(a3),
                   "+v"(a4),"+v"(a5),"+v"(a6),"+v"(a7) :: "memory");
}
__device__ __forceinline__ void lgkm0_bar(){
    asm volatile("s_waitcnt lgkmcnt(0)" ::: "memory");
    __builtin_amdgcn_s_barrier();
}

// init: W_hh -> A-frags (hi/lo), tile row = unit*4 + gate; h0 -> hfrag[0]; zero u32s.
__global__ void rnn_init_kernel(const float* __restrict__ W_hh,
                                const float* __restrict__ h0,
                                char* __restrict__ wsb) {
    int idx = blockIdx.x * blockDim.x + threadIdx.x;   // 0 .. 1048575
    {
        int i  = idx & 7;
        int l  = (idx >> 3) & 63;
        int kt = (idx >> 9) & 15;
        int rb = (idx >> 13) & 3;
        int wl = idx >> 15;
        int mm = l & 15, gg = l >> 4;
        int gt = mm & 3, lu = mm >> 2;               // tile row mm = lu*4 + gt
        int grow = gt * 512 + wl * 16 + rb * 4 + lu;
        int k = kt * 32 + gg * 8 + i;
        float v = W_hh[grow * 512 + k];
        unsigned short hi = bf16hi_rne(v);
        float fh = __uint_as_float(((unsigned)hi) << 16);
        unsigned short lo = bf16hi_rne(v - fh);
        ((unsigned short*)(wsb + WF_HI_B))[idx] = hi;
        ((unsigned short*)(wsb + WF_LO_B))[idx] = lo;
    }
    if (idx < 524288) {   // hfrag par 0: [cl8][kt16][arr2][g4][col64][i8]
        int i   = idx & 7;
        int gg  = (idx >> 9) & 3;
        int arr = (idx >> 11) & 1;
        int kt  = (idx >> 12) & 15;
        int cl  = idx >> 16;
        int rem = idx & 65535;
        int j = kt * 32 + gg * 8 + i;
        float v = h0[j];
        unsigned short hi = bf16hi_rne(v);
        unsigned short w = hi;
        if (arr) {
            float fh = __uint_as_float(((unsigned)hi) << 16);
            w = bf16hi_rne(v - fh);
        }
        ((unsigned short*)(wsb + HFRAG_B + (unsigned)cl * 131072u))[rem] = w;
    }
    if (idx < 2048) ((unsigned int*)(wsb + U32_B))[idx] = 0u;
}

__global__ __attribute__((amdgpu_waves_per_eu(2, 2))) __launch_bounds__(THREADS)
void rnn_persist_kernel(const float* __restrict__ x,
                        const float* __restrict__ W_ih,
                        const float* __restrict__ b_ih,
                        const float* __restrict__ b_hh,
                        const float* __restrict__ fc_W,
                        const float* __restrict__ fc_b,
                        const float* __restrict__ c0,
                        char* __restrict__ wsb,
                        float* __restrict__ out) {
    __shared__ float smem[L_TOT];
    char* ldsst = (char*)smem;          // staging at byte 0 (128 KB)

    const int wg  = blockIdx.x;
    const int cl  = wg & 7;             // cluster -> XCD cl under round-robin
    const int wl  = wg >> 3;            // 0..31
    const int j0  = wl * 16;
    const int nb0 = cl * 64;
    const int tid = threadIdx.x;
    const int lane = tid & 63;
    const int wid  = tid >> 6;          // 0..7
    const int rb   = wid & 3;           // row-tile (unit block)
    const int kh   = wid >> 2;          // K-half 0/1
    const int m    = lane & 15;
    const int g    = lane >> 4;
    const int gu   = wl * 16 + rb * 4 + g;   // this lane's global hidden unit
    const int c0i  = kh * 32 + m;            // cell col (and +16)

    unsigned int* flags = (unsigned int*)(wsb + U32_B);        // [cl*32 + wl]
    unsigned int* ctr   = (unsigned int*)(wsb + U32_B + 3072);
    unsigned int* xccb  = (unsigned int*)(wsb + U32_B + 4096); // [wg]

    // ---- one-time: wih to LDS ----
    for (int i2 = tid; i2 < 16 * 36; i2 += THREADS) {
        int u = i2 / 36; int r2 = i2 - u * 36; int gt = r2 / 9; int d = r2 - gt * 9;
        smem[L_WIH + u * 40 + gt * 9 + d] = W_ih[(gt * 512 + wl * 16 + u) * DD + d];
    }

    // ---- one-time: per-lane registers: bias (4), c-state (2) ----
    const float bias0 = b_ih[gu]        + b_hh[gu];
    const float bias1 = b_ih[512 + gu]  + b_hh[512 + gu];
    const float bias2 = b_ih[1024 + gu] + b_hh[1024 + gu];
    const float bias3 = b_ih[1536 + gu] + b_hh[1536 + gu];
    float creg0 = c0[gu], creg1 = c0[gu];

    // ---- one-time: W A-frags for THIS wave's K-half (hi + lo): 64 VGPRs ----
    s8v wAh[8], wAl[8];
    {
        const char* base = wsb + (unsigned)(((wl*4 + rb)*16 + kh*8)*64 + lane)*16u;
#pragma unroll
        for (int j = 0; j < 8; ++j) {
            wAh[j] = *(const s8v*)(base + WF_HI_B + j*1024);
            wAl[j] = *(const s8v*)(base + WF_LO_B + j*1024);
        }
    }

    // ---- startup: publish XCD id, grid barrier, co-location check ----
    if (tid == 0) {
        unsigned xcc;
        asm volatile("s_getreg_b32 %0, hwreg(HW_REG_XCC_ID, 0, 32)" : "=s"(xcc));
        __hip_atomic_store(xccb + wg, xcc + 1u, __ATOMIC_RELAXED, __HIP_MEMORY_SCOPE_AGENT);
        __hip_atomic_fetch_add(ctr, 1u, __ATOMIC_RELEASE, __HIP_MEMORY_SCOPE_AGENT);
        while (__hip_atomic_load(ctr, __ATOMIC_RELAXED, __HIP_MEMORY_SCOPE_AGENT) < NWG)
            __builtin_amdgcn_s_sleep(8);
    }
    __syncthreads();
    {
        unsigned v = (tid < WPC)
            ? __hip_atomic_load(xccb + cl + 8 * tid, __ATOMIC_RELAXED,
                                __HIP_MEMORY_SCOPE_AGENT) : 0u;
        unsigned v0 = __shfl(v, 0, 64);
        bool ok = (tid >= WPC) || (v != 0u && v == v0);
        unsigned long long mk = __ballot(ok);
        if (tid == 0) smem[L_MISC] = (mk == ~0ull) ? 1.0f : 0.0f;
    }
    __syncthreads();
    const bool fast = (smem[L_MISC] != 0.0f);

    const int fg = tid >> 4, fl = tid & 15;

    for (int s = 0; s < NSTEP; ++s) {
        const int par = s & 1;
        const char* hsrc = wsb + HFRAG_B + (unsigned)(par*8 + cl) * 131072u;
        unsigned int* flg = flags + cl * 32;
        const bool dec = (s >= TP1 + 1);
        const bool enc = (s < TP1);

        // ---- A. step wait: per-lane atomic poll ----
        if (s > 0) {
            if (tid < WPC) {
                for (;;) {
                    unsigned v = __hip_atomic_load(flg + tid, __ATOMIC_RELAXED,
                                                   __HIP_MEMORY_SCOPE_AGENT);
                    if (__all((int)(v >= (unsigned)s))) break;
                    __builtin_amdgcn_s_sleep(2);
                }
            }
            __syncthreads();
            if (fast) __builtin_amdgcn_fence(__ATOMIC_ACQUIRE, "workgroup");
            else      __builtin_amdgcn_fence(__ATOMIC_ACQUIRE, "agent");
        }

        // ---- B. issue phase-A hfrag loads (kt 0-7) ----
        i4v hb[8];
#pragma unroll
        for (int c = 0; c < 8; ++c)
            ld16i(hb[c], hsrc + c*8192 + tid*16);

        // ---- C. x loads for this lane's two batches (encode) ----
        float xv0[DD], xv1[DD];
        if (enc) {
            const float* xp0 = x + (size_t)(nb0 + c0i) * (TP1 * DD) + s * DD;
            const float* xp1 = x + (size_t)(nb0 + c0i + 16) * (TP1 * DD) + s * DD;
#pragma unroll
            for (int d = 0; d < DD; ++d) { xv0[d] = xp0[d]; xv1[d] = xp1[d]; }
        }

        // ---- D. stage phase A; then issue phase-B loads (latency hides under GEMM A) ----
        wait_vm0_mem();
#pragma unroll
        for (int c = 0; c < 8; ++c)
            *(i4v*)(ldsst + c*8192 + tid*16) = hb[c];
#pragma unroll
        for (int c = 0; c < 8; ++c)
            ld16i(hb[c], hsrc + (c+8)*8192 + tid*16);
        lgkm0_bar();                         // bar1: phase A staged

        // ---- E. GEMM phase A (kh==0 waves), K = 0..255 ----
        f4v a0 = {0,0,0,0}, a1 = {0,0,0,0}, a2 = {0,0,0,0}, a3 = {0,0,0,0};
        if (kh == 0) {
#pragma unroll
            for (int j = 0; j < 8; ++j) {
                const char* bb = ldsst + j*8192 + g*1024 + m*16;
                s8v bh0 = *(const s8v*)(bb);
                s8v bh1 = *(const s8v*)(bb + 256);
                s8v bh2 = *(const s8v*)(bb + 512);
                s8v bh3 = *(const s8v*)(bb + 768);
                s8v bl0 = *(const s8v*)(bb + 4096);
                s8v bl1 = *(const s8v*)(bb + 4096 + 256);
                s8v bl2 = *(const s8v*)(bb + 4096 + 512);
                s8v bl3 = *(const s8v*)(bb + 4096 + 768);
                a0 = __builtin_amdgcn_mfma_f32_16x16x32_bf16(wAh[j], bh0, a0, 0,0,0);
                a1 = __builtin_amdgcn_mfma_f32_16x16x32_bf16(wAh[j], bh1, a1, 0,0,0);
                a2 = __builtin_amdgcn_mfma_f32_16x16x32_bf16(wAh[j], bh2, a2, 0,0,0);
                a3 = __builtin_amdgcn_mfma_f32_16x16x32_bf16(wAh[j], bh3, a3, 0,0,0);
                a0 = __builtin_amdgcn_mfma_f32_16x16x32_bf16(wAl[j], bh0, a0, 0,0,0);
                a1 = __builtin_amdgcn_mfma_f32_16x16x32_bf16(wAl[j], bh1, a1, 0,0,0);
                a2 = __builtin_amdgcn_mfma_f32_16x16x32_bf16(wAl[j], bh2, a2, 0,0,0);
                a3 = __builtin_amdgcn_mfma_f32_16x16x32_bf16(wAl[j], bh3, a3, 0,0,0);
                a0 = __builtin_amdgcn_mfma_f32_16x16x32_bf16(wAh[j], bl0, a0, 0,0,0);
                a1 = __builtin_amdgcn_mfma_f32_16x16x32_bf16(wAh[j], bl1, a1, 0,0,0);
                a2 = __builtin_amdgcn_mfma_f32_16x16x32_bf16(wAh[j], bl2, a2, 0,0,0);
                a3 = __builtin_amdgcn_mfma_f32_16x16x32_bf16(wAh[j], bl3, a3, 0,0,0);
            }
            // publish this K-half's cols-32..63 partials
            float* pe = smem + L_EX + ((rb*2 + 0)*64 + lane)*8;
            *(f4v*)(pe)     = a2;
            *(f4v*)(pe + 4) = a3;
        }

        // ---- F. stage phase B (all threads) ----
        wait_vm0_mem();
#pragma unroll
        for (int c = 0; c < 8; ++c)
            *(i4v*)(ldsst + (c+8)*8192 + tid*16) = hb[c];

        // ---- G. fc hrow loads (decode) — contiguous 32 floats/lane, 16-B steps ----
        f4v q0,q1,q2,q3,q4,q5,q6,q7;
        if (dec) {
            const int bselL = (fg < 2 * DD) ? (fg / DD) : 0;
            const char* hp = wsb + HROW_B + (unsigned)(par*8 + cl)*131072u
                             + (unsigned)((wl*2 + bselL)*512 + fl*32)*4u;
            ld16f(q0, hp);      ld16f(q1, hp+16);  ld16f(q2, hp+32);  ld16f(q3, hp+48);
            ld16f(q4, hp+64);   ld16f(q5, hp+80);  ld16f(q6, hp+96);  ld16f(q7, hp+112);
        }
        lgkm0_bar();                         // bar2: phase B staged; kh0 exch published

        // ---- H. GEMM phase B (kh==1 waves), K = 256..511 ----
        if (kh == 1) {
#pragma unroll
            for (int j = 0; j < 8; ++j) {
                const char* bb = ldsst + (8+j)*8192 + g*1024 + m*16;
                s8v bh0 = *(const s8v*)(bb);
                s8v bh1 = *(const s8v*)(bb + 256);
                s8v bh2 = *(const s8v*)(bb + 512);
                s8v bh3 = *(const s8v*)(bb + 768);
                s8v bl0 = *(const s8v*)(bb + 4096);
                s8v bl1 = *(const s8v*)(bb + 4096 + 256);
                s8v bl2 = *(const s8v*)(bb + 4096 + 512);
                s8v bl3 = *(const s8v*)(bb + 4096 + 768);
                a0 = __builtin_amdgcn_mfma_f32_16x16x32_bf16(wAh[j], bh0, a0, 0,0,0);
                a1 = __builtin_amdgcn_mfma_f32_16x16x32_bf16(wAh[j], bh1, a1, 0,0,0);
                a2 = __builtin_amdgcn_mfma_f32_16x16x32_bf16(wAh[j], bh2, a2, 0,0,0);
                a3 = __builtin_amdgcn_mfma_f32_16x16x32_bf16(wAh[j], bh3, a3, 0,0,0);
                a0 = __builtin_amdgcn_mfma_f32_16x16x32_bf16(wAl[j], bh0, a0, 0,0,0);
                a1 = __builtin_amdgcn_mfma_f32_16x16x32_bf16(wAl[j], bh1, a1, 0,0,0);
                a2 = __builtin_amdgcn_mfma_f32_16x16x32_bf16(wAl[j], bh2, a2, 0,0,0);
                a3 = __builtin_amdgcn_mfma_f32_16x16x32_bf16(wAl[j], bh3, a3, 0,0,0);
                a0 = __builtin_amdgcn_mfma_f32_16x16x32_bf16(wAh[j], bl0, a0, 0,0,0);
                a1 = __builtin_amdgcn_mfma_f32_16x16x32_bf16(wAh[j], bl1, a1, 0,0,0);
                a2 = __builtin_amdgcn_mfma_f32_16x16x32_bf16(wAh[j], bl2, a2, 0,0,0);
                a3 = __builtin_amdgcn_mfma_f32_16x16x32_bf16(wAh[j], bl3, a3, 0,0,0);
            }
            float* pe = smem + L_EX + ((rb*2 + 1)*64 + lane)*8;
            *(f4v*)(pe)     = a0;
            *(f4v*)(pe + 4) = a1;
        }
        lgkm0_bar();                         // bar3: all exch published

        // ---- I. combine K-halves; cell in registers ----
        {
            const float* px = smem + L_EX + ((rb*2 + (kh^1))*64 + lane)*8;
            f4v r0 = *(const f4v*)(px);
            f4v r1 = *(const f4v*)(px + 4);
            f4v ka, kb;
            if (kh == 0) { ka = a0 + r0; kb = a1 + r1; }
            else         { ka = a2 + r0; kb = a3 + r1; }

            float s00=0,s01=0,s02=0,s03=0, s10=0,s11=0,s12=0,s13=0;
            if (enc) {
                const float* wb2 = smem + L_WIH + (rb*4 + g) * 40;
#pragma unroll
                for (int r2 = 0; r2 < 9; ++r2) {
                    f4v w4 = *(const f4v*)(wb2 + r2*4);
#pragma unroll
                    for (int e = 0; e < 4; ++e) {
                        const int fl2 = r2*4 + e;
                        const int gt = fl2 / 9, d = fl2 - gt*9;
                        const float w = w4[e];
                        const float p0 = xv0[d] * w, p1 = xv1[d] * w;
                        if (gt == 0) { s00 += p0; s10 += p1; }
                        else if (gt == 1) { s01 += p0; s11 += p1; }
                        else if (gt == 2) { s02 += p0; s12 += p1; }
                        else { s03 += p0; s13 += p1; }
                    }
                }
            }
            {
                float vi = ka.x + bias0 + s00, vf = ka.y + bias1 + s01;
                float vg = ka.z + bias2 + s02, vo = ka.w + bias3 + s03;
                float cn = sigmoidf_(vf) * creg0 + sigmoidf_(vi) * tanhf_(vg);
                creg0 = cn;
                smem[L_HNEW + (rb*4 + g) * 65 + c0i] = sigmoidf_(vo) * tanhf_(cn);
            }
            {
                float vi = kb.x + bias0 + s10, vf = kb.y + bias1 + s11;
                float vg = kb.z + bias2 + s12, vo = kb.w + bias3 + s13;
                float cn = sigmoidf_(vf) * creg1 + sigmoidf_(vi) * tanhf_(vg);
                creg1 = cn;
                smem[L_HNEW + (rb*4 + g) * 65 + c0i + 16] = sigmoidf_(vo) * tanhf_(cn);
            }
        }
        lgkm0_bar();                         // bar4: hnew visible

        // ---- J. hrow write + pack hfrag for next step ----
        {
            float* hrp = (float*)(wsb + HROW_B + (unsigned)((par^1)*8 + cl)*131072u);
            const int kl = tid & 15, nl0 = tid >> 4;
#pragma unroll
            for (int i = 0; i < 2; ++i) {
                const int nl = nl0 + i * 32;
                hrp[nl * 512 + j0 + kl] = smem[L_HNEW + kl * 65 + nl];
            }
        }
        if (tid < 256) {
            const int col = tid & 63, jblk = (tid >> 6) & 1, arr = (tid >> 7) & 1;
            const int kt = wl >> 1, gg = (wl & 1) * 2 + jblk;
            s8v v;
#pragma unroll
            for (int i = 0; i < 8; ++i) {
                float f = smem[L_HNEW + (jblk * 8 + i) * 65 + col];
                unsigned short hi = bf16hi_rne(f);
                unsigned short w = hi;
                if (arr) {
                    float fh = __uint_as_float(((unsigned)hi) << 16);
                    w = bf16hi_rne(f - fh);
                }
                v[i] = (short)w;
            }
            char* dst = wsb + HFRAG_B + (unsigned)((par^1)*8 + cl)*131072u
                        + (unsigned)(kt*8192 + arr*4096 + gg*1024 + col*16);
            *(s8v*)dst = v;
        }
        wait_vm0_mem();   // drains hrow/pack stores (q loads also complete here)
        __syncthreads();

        // ---- K. signal ----
        if (tid == 0) {
            if (fast) {
                __hip_atomic_store(flg + wl, (unsigned)(s + 1),
                                   __ATOMIC_RELAXED, __HIP_MEMORY_SCOPE_AGENT);
            } else {
                __builtin_amdgcn_fence(__ATOMIC_RELEASE, "agent");
                __hip_atomic_store(flg + wl, (unsigned)(s + 1),
                                   __ATOMIC_RELEASE, __HIP_MEMORY_SCOPE_AGENT);
            }
        }

        // ---- L. fc compute for h(s) (decode): out[:, s-258, :] ----
        if (dec && fg < 2 * DD) {
            const int bsel = fg / DD, d = fg - bsel * DD;
            const int bl = wl * 2 + bsel;
            const f4v* wv = (const f4v*)(fc_W + d * HH + fl * 32);
            wait_vm0_8f(q0,q1,q2,q3,q4,q5,q6,q7);   // operand-tied: no hoist past waitcnt
            float acc = 0.f;
            acc += q0.x*wv[0].x + q0.y*wv[0].y + q0.z*wv[0].z + q0.w*wv[0].w;
            acc += q1.x*wv[1].x + q1.y*wv[1].y + q1.z*wv[1].z + q1.w*wv[1].w;
            acc += q2.x*wv[2].x + q2.y*wv[2].y + q2.z*wv[2].z + q2.w*wv[2].w;
            acc += q3.x*wv[3].x + q3.y*wv[3].y + q3.z*wv[3].z + q3.w*wv[3].w;
            acc += q4.x*wv[4].x + q4.y*wv[4].y + q4.z*wv[4].z + q4.w*wv[4].w;
            acc += q5.x*wv[5].x + q5.y*wv[5].y + q5.z*wv[5].z + q5.w*wv[5].w;
            acc += q6.x*wv[6].x + q6.y*wv[6].y + q6.z*wv[6].z + q6.w*wv[6].w;
            acc += q7.x*wv[7].x + q7.y*wv[7].y + q7.z*wv[7].z + q7.w*wv[7].w;
            acc += __shfl_down(acc, 8, 16);
            acc += __shfl_down(acc, 4, 16);
            acc += __shfl_down(acc, 2, 16);
            acc += __shfl_down(acc, 1, 16);
            if (fl == 0)
                out[(size_t)(nb0 + bl) * (TT * DD) + (s - (TP1 + 1)) * DD + d] =
                    1.0f / (1.0f + __expf(-(acc + fc_b[d])));
        }
    }

    // ---- tail fc: td = 255 from h(513) ----
    {
        if (tid < WPC) {
            for (;;) {
                unsigned v = __hip_atomic_load(flags + cl * 32 + tid,
                                               __ATOMIC_RELAXED, __HIP_MEMORY_SCOPE_AGENT);
                if (__all((int)(v >= (unsigned)NSTEP))) break;
                __builtin_amdgcn_s_sleep(2);
            }
        }
        __syncthreads();
        if (fast) __builtin_amdgcn_fence(__ATOMIC_ACQUIRE, "workgroup");
        else      __builtin_amdgcn_fence(__ATOMIC_ACQUIRE, "agent");

        if (fg < 2 * DD) {
            const int bsel = fg / DD, d = fg - bsel * DD;
            const int bl = wl * 2 + bsel;
            const char* hp = wsb + HROW_B + (unsigned)((NSTEP & 1)*8 + cl)*131072u
                             + (unsigned)(bl*512 + fl*32)*4u;
            f4v q0,q1,q2,q3,q4,q5,q6,q7;
            ld16f(q0, hp);      ld16f(q1, hp+16);  ld16f(q2, hp+32);  ld16f(q3, hp+48);
            ld16f(q4, hp+64);   ld16f(q5, hp+80);  ld16f(q6, hp+96);  ld16f(q7, hp+112);
            const f4v* wv = (const f4v*)(fc_W + d * HH + fl * 32);
            wait_vm0_8f(q0,q1,q2,q3,q4,q5,q6,q7);
            float acc = 0.f;
            acc += q0.x*wv[0].x + q0.y*wv[0].y + q0.z*wv[0].z + q0.w*wv[0].w;
            acc += q1.x*wv[1].x + q1.y*wv[1].y + q1.z*wv[1].z + q1.w*wv[1].w;
            acc += q2.x*wv[2].x + q2.y*wv[2].y + q2.z*wv[2].z + q2.w*wv[2].w;
            acc += q3.x*wv[3].x + q3.y*wv[3].y + q3.z*wv[3].z + q3.w*wv[3].w;
            acc += q4.x*wv[4].x + q4.y*wv[4].y + q4.z*wv[4].z + q4.w*wv[4].w;
            acc += q5.x*wv[5].x + q5.y*wv[5].y + q5.z*wv[5].z + q5.w*wv[5].w;
            acc += q6.x*wv[6].x + q6.y*wv[6].y + q6.z*wv[6].z + q6.w*wv[6].w;
            acc += q7.x*wv[7].x + q7.y*wv[7].y + q7.z*wv[7].z + q7.w*wv[7].w;
            acc += __shfl_down(acc, 8, 16);
            acc += __shfl_down(acc, 4, 16);
            acc += __shfl_down(acc, 2, 16);
            acc += __shfl_down(acc, 1, 16);
            if (fl == 0)
                out[(size_t)(nb0 + bl) * (TT * DD) + 255 * DD + d] =
                    1.0f / (1.0f + __expf(-(acc + fc_b[d])));
        }
    }
}

extern "C" void kernel_launch(void* const* d_in, const int* in_sizes, int n_in,
                              void* d_out, int out_size, void* d_ws, size_t ws_size,
                              hipStream_t stream) {
    (void)in_sizes; (void)n_in; (void)out_size; (void)ws_size;
    const float* x    = (const float*)d_in[0];
    const float* W_ih = (const float*)d_in[1];
    const float* W_hh = (const float*)d_in[2];
    const float* b_ih = (const float*)d_in[3];
    const float* b_hh = (const float*)d_in[4];
    const float* fc_W = (const float*)d_in[5];
    const float* fc_b = (const float*)d_in[6];
    const float* h0   = (const float*)d_in[7];
    const float* c0   = (const float*)d_in[8];
    float* out = (float*)d_out;
    char*  wsb = (char*)d_ws;

    hipLaunchKernelGGL(rnn_init_kernel, dim3(4096), dim3(256), 0, stream,
                       W_hh, h0, wsb);
    hipLaunchKernelGGL(rnn_persist_kernel, dim3(NWG), dim3(THREADS), 0, stream,
                       x, W_ih, b_ih, b_hh, fc_W, fc_b, c0, wsb, out);
}

// Round 15
// 2438.948 us; speedup vs baseline: 3.3109x; 1.3591x over previous
//
#include <hip/hip_runtime.h>

// N=512 batch, T=256, H=512, D=9. 257 encode + 256 decode steps, LSTM + fc(sigmoid).
// Persistent kernel: 256 wgs x 512 threads (1 wg/CU), 8 clusters x 32 wgs (cl = wg&7 -> one
// XCD). 8 waves = 4 row-tiles x 2 K-halves (W frags 64 VGPR/wave; no spill; partials via LDS
// exchange). In-register LSTM cell. amdgpu_waves_per_eu(2,2) pins 2 waves/EU (256-reg cap).
// R15: 2-term MFMA (Ah*Bh + Al*Bh — W fp32-exact, h bf16): halves LDS reads, staging, and
// MFMA count vs R14's 3-term. fc reads bf16 hfrag directly (no HROW buffer). Expected
// absmax ~1e-3 (first non-exact round), threshold 1.05e-2.

#define TT 256
#define HH 512
#define DD 9
#define TP1 257
#define NSTEP 513
#define THREADS 512
#define NWG 256
#define NCL 8
#define WPC 32

// ws byte offsets
#define WF_HI_B 0u          // Wfrag hi: [wl32][rb4][kt16][lane64][i8] bf16 = 2 MB
#define WF_LO_B 2097152u    // Wfrag lo: 2 MB
#define HFRAG_B 4194304u    // hfrag: [par2][cl8] x 65536 B ([kt16][g4][col64][i8] bf16, hi only)
#define U32_B   8388608u    // flags[256] | ctr @+3072 | xcc @+4096

// LDS float offsets (22164 floats = 86.6 KB; 1 wg/CU)
#define L_ST    0           // staging: 16 kt x 4096 B = 16384 floats
#define L_EX    16384       // acc exchange: 8 slots x 64 lanes x 8 f = 4096 floats
#define L_HNEW  20480       // hnew[u16][65]
#define L_WIH   21520       // wih[u16][40]
#define L_MISC  22160
#define L_TOT   22164

typedef short s8v __attribute__((ext_vector_type(8)));
typedef float f4v __attribute__((ext_vector_type(4)));
typedef int   i4v __attribute__((ext_vector_type(4)));

__device__ __forceinline__ float sigmoidf_(float v){ return 1.0f/(1.0f+__expf(-v)); }
__device__ __forceinline__ float tanhf_(float v){ return 1.0f - 2.0f/(__expf(2.0f*v)+1.0f); }
__device__ __forceinline__ unsigned short bf16hi_rne(float f){
    unsigned u = __float_as_uint(f);
    return (unsigned short)((u + 0x7fffu + ((u>>16)&1u)) >> 16);
}
#define B2F_LO(u) __uint_as_float(((unsigned)(u))<<16)
#define B2F_HI(u) __uint_as_float(((unsigned)(u)) & 0xffff0000u)

__device__ __forceinline__ void ld16i(i4v& d, const char* p){
    asm volatile("global_load_dwordx4 %0, %1, off sc0" : "=v"(d) : "v"(p));
}
__device__ __forceinline__ void wait_vm0_mem(){
    asm volatile("s_waitcnt vmcnt(0)" ::: "memory");
}
__device__ __forceinline__ void wait_vm0_4i(i4v& a0,i4v& a1,i4v& a2,i4v& a3){
    asm volatile("s_waitcnt vmcnt(0)"
                 : "+v"(a0),"+v"(a1),"+v"(a2),"+v"(a3) :: "memory");
}
__device__ __forceinline__ void lgkm0_bar(){
    asm volatile("s_waitcnt lgkmcnt(0)" ::: "memory");
    __builtin_amdgcn_s_barrier();
}

// init: W_hh -> A-frags (hi/lo), tile row = unit*4 + gate; h0 -> hfrag[0] (hi only); zero u32s.
__global__ void rnn_init_kernel(const float* __restrict__ W_hh,
                                const float* __restrict__ h0,
                                char* __restrict__ wsb) {
    int idx = blockIdx.x * blockDim.x + threadIdx.x;   // 0 .. 1048575
    {
        int i  = idx & 7;
        int l  = (idx >> 3) & 63;
        int kt = (idx >> 9) & 15;
        int rb = (idx >> 13) & 3;
        int wl = idx >> 15;
        int mm = l & 15, gg = l >> 4;
        int gt = mm & 3, lu = mm >> 2;               // tile row mm = lu*4 + gt
        int grow = gt * 512 + wl * 16 + rb * 4 + lu;
        int k = kt * 32 + gg * 8 + i;
        float v = W_hh[grow * 512 + k];
        unsigned short hi = bf16hi_rne(v);
        float fh = __uint_as_float(((unsigned)hi) << 16);
        unsigned short lo = bf16hi_rne(v - fh);
        ((unsigned short*)(wsb + WF_HI_B))[idx] = hi;
        ((unsigned short*)(wsb + WF_LO_B))[idx] = lo;
    }
    if (idx < 262144) {   // hfrag par 0: [cl8][kt16][g4][col64][i8], hi only
        int i   = idx & 7;
        int gg  = (idx >> 9) & 3;
        int kt  = (idx >> 11) & 15;
        int cl  = idx >> 15;
        int rem = idx & 32767;
        int j = kt * 32 + gg * 8 + i;
        ((unsigned short*)(wsb + HFRAG_B + (unsigned)cl * 65536u))[rem] = bf16hi_rne(h0[j]);
    }
    if (idx < 2048) ((unsigned int*)(wsb + U32_B))[idx] = 0u;
}

__global__ __attribute__((amdgpu_waves_per_eu(2, 2))) __launch_bounds__(THREADS)
void rnn_persist_kernel(const float* __restrict__ x,
                        const float* __restrict__ W_ih,
                        const float* __restrict__ b_ih,
                        const float* __restrict__ b_hh,
                        const float* __restrict__ fc_W,
                        const float* __restrict__ fc_b,
                        const float* __restrict__ c0,
                        char* __restrict__ wsb,
                        float* __restrict__ out) {
    __shared__ float smem[L_TOT];
    char* ldsst = (char*)smem;          // staging at byte 0 (64 KB)

    const int wg  = blockIdx.x;
    const int cl  = wg & 7;             // cluster -> XCD cl under round-robin
    const int wl  = wg >> 3;            // 0..31
    const int j0  = wl * 16;
    const int nb0 = cl * 64;
    const int tid = threadIdx.x;
    const int lane = tid & 63;
    const int wid  = tid >> 6;          // 0..7
    const int rb   = wid & 3;           // row-tile (unit block)
    const int kh   = wid >> 2;          // K-half 0/1
    const int m    = lane & 15;
    const int g    = lane >> 4;
    const int gu   = wl * 16 + rb * 4 + g;   // this lane's global hidden unit
    const int c0i  = kh * 32 + m;            // cell col (and +16)

    unsigned int* flags = (unsigned int*)(wsb + U32_B);        // [cl*32 + wl]
    unsigned int* ctr   = (unsigned int*)(wsb + U32_B + 3072);
    unsigned int* xccb  = (unsigned int*)(wsb + U32_B + 4096); // [wg]

    // ---- one-time: wih to LDS ----
    for (int i2 = tid; i2 < 16 * 36; i2 += THREADS) {
        int u = i2 / 36; int r2 = i2 - u * 36; int gt = r2 / 9; int d = r2 - gt * 9;
        smem[L_WIH + u * 40 + gt * 9 + d] = W_ih[(gt * 512 + wl * 16 + u) * DD + d];
    }

    // ---- one-time: per-lane registers: bias (4), c-state (2) ----
    const float bias0 = b_ih[gu]        + b_hh[gu];
    const float bias1 = b_ih[512 + gu]  + b_hh[512 + gu];
    const float bias2 = b_ih[1024 + gu] + b_hh[1024 + gu];
    const float bias3 = b_ih[1536 + gu] + b_hh[1536 + gu];
    float creg0 = c0[gu], creg1 = c0[gu];

    // ---- one-time: W A-frags for THIS wave's K-half (hi + lo): 64 VGPRs ----
    s8v wAh[8], wAl[8];
    {
        const char* base = wsb + (unsigned)(((wl*4 + rb)*16 + kh*8)*64 + lane)*16u;
#pragma unroll
        for (int j = 0; j < 8; ++j) {
            wAh[j] = *(const s8v*)(base + WF_HI_B + j*1024);
            wAl[j] = *(const s8v*)(base + WF_LO_B + j*1024);
        }
    }

    // ---- startup: publish XCD id, grid barrier, co-location check ----
    if (tid == 0) {
        unsigned xcc;
        asm volatile("s_getreg_b32 %0, hwreg(HW_REG_XCC_ID, 0, 32)" : "=s"(xcc));
        __hip_atomic_store(xccb + wg, xcc + 1u, __ATOMIC_RELAXED, __HIP_MEMORY_SCOPE_AGENT);
        __hip_atomic_fetch_add(ctr, 1u, __ATOMIC_RELEASE, __HIP_MEMORY_SCOPE_AGENT);
        while (__hip_atomic_load(ctr, __ATOMIC_RELAXED, __HIP_MEMORY_SCOPE_AGENT) < NWG)
            __builtin_amdgcn_s_sleep(8);
    }
    __syncthreads();
    {
        unsigned v = (tid < WPC)
            ? __hip_atomic_load(xccb + cl + 8 * tid, __ATOMIC_RELAXED,
                                __HIP_MEMORY_SCOPE_AGENT) : 0u;
        unsigned v0 = __shfl(v, 0, 64);
        bool ok = (tid >= WPC) || (v != 0u && v == v0);
        unsigned long long mk = __ballot(ok);
        if (tid == 0) smem[L_MISC] = (mk == ~0ull) ? 1.0f : 0.0f;
    }
    __syncthreads();
    const bool fast = (smem[L_MISC] != 0.0f);

    const int fg = tid >> 4, fl = tid & 15;

    for (int s = 0; s < NSTEP; ++s) {
        const int par = s & 1;
        const char* hsrc = wsb + HFRAG_B + (unsigned)(par*8 + cl) * 65536u;
        unsigned int* flg = flags + cl * 32;
        const bool dec = (s >= TP1 + 1);
        const bool enc = (s < TP1);

        // ---- A. step wait: per-lane atomic poll ----
        if (s > 0) {
            if (tid < WPC) {
                for (;;) {
                    unsigned v = __hip_atomic_load(flg + tid, __ATOMIC_RELAXED,
                                                   __HIP_MEMORY_SCOPE_AGENT);
                    if (__all((int)(v >= (unsigned)s))) break;
                    __builtin_amdgcn_s_sleep(2);
                }
            }
            __syncthreads();
            if (fast) __builtin_amdgcn_fence(__ATOMIC_ACQUIRE, "workgroup");
            else      __builtin_amdgcn_fence(__ATOMIC_ACQUIRE, "agent");
        }

        // ---- B. issue phase-A hfrag loads (kt 0-7 = 32 KB; 4 x b128/thread) ----
        i4v hb[4];
#pragma unroll
        for (int c = 0; c < 4; ++c)
            ld16i(hb[c], hsrc + c*8192 + tid*16);

        // ---- C. x loads for this lane's two batches (encode) ----
        float xv0[DD], xv1[DD];
        if (enc) {
            const float* xp0 = x + (size_t)(nb0 + c0i) * (TP1 * DD) + s * DD;
            const float* xp1 = x + (size_t)(nb0 + c0i + 16) * (TP1 * DD) + s * DD;
#pragma unroll
            for (int d = 0; d < DD; ++d) { xv0[d] = xp0[d]; xv1[d] = xp1[d]; }
        }

        // ---- D. stage phase A; then issue phase-B loads ----
        wait_vm0_mem();
#pragma unroll
        for (int c = 0; c < 4; ++c)
            *(i4v*)(ldsst + c*8192 + tid*16) = hb[c];
#pragma unroll
        for (int c = 0; c < 4; ++c)
            ld16i(hb[c], hsrc + 32768 + c*8192 + tid*16);
        lgkm0_bar();                         // bar1: phase A staged

        // ---- E. GEMM phase A (kh==0 waves), K = 0..255, 2-term ----
        f4v a0 = {0,0,0,0}, a1 = {0,0,0,0}, a2 = {0,0,0,0}, a3 = {0,0,0,0};
        if (kh == 0) {
#pragma unroll
            for (int j = 0; j < 8; ++j) {
                const char* bb = ldsst + j*4096 + g*1024 + m*16;
                s8v bh0 = *(const s8v*)(bb);
                s8v bh1 = *(const s8v*)(bb + 256);
                s8v bh2 = *(const s8v*)(bb + 512);
                s8v bh3 = *(const s8v*)(bb + 768);
                a0 = __builtin_amdgcn_mfma_f32_16x16x32_bf16(wAh[j], bh0, a0, 0,0,0);
                a1 = __builtin_amdgcn_mfma_f32_16x16x32_bf16(wAh[j], bh1, a1, 0,0,0);
                a2 = __builtin_amdgcn_mfma_f32_16x16x32_bf16(wAh[j], bh2, a2, 0,0,0);
                a3 = __builtin_amdgcn_mfma_f32_16x16x32_bf16(wAh[j], bh3, a3, 0,0,0);
                a0 = __builtin_amdgcn_mfma_f32_16x16x32_bf16(wAl[j], bh0, a0, 0,0,0);
                a1 = __builtin_amdgcn_mfma_f32_16x16x32_bf16(wAl[j], bh1, a1, 0,0,0);
                a2 = __builtin_amdgcn_mfma_f32_16x16x32_bf16(wAl[j], bh2, a2, 0,0,0);
                a3 = __builtin_amdgcn_mfma_f32_16x16x32_bf16(wAl[j], bh3, a3, 0,0,0);
            }
            // publish this K-half's cols-32..63 partials
            float* pe = smem + L_EX + ((rb*2 + 0)*64 + lane)*8;
            *(f4v*)(pe)     = a2;
            *(f4v*)(pe + 4) = a3;
        }

        // ---- F. stage phase B (all threads) ----
        wait_vm0_mem();
#pragma unroll
        for (int c = 0; c < 4; ++c)
            *(i4v*)(ldsst + 32768 + c*8192 + tid*16) = hb[c];

        // ---- G. fc hfrag loads (decode; bf16 h, k-contiguous) ----
        i4v qa0, qa1, qa2, qa3;
        if (dec) {
            const int bselL = (fg < 2 * DD) ? (fg / DD) : 0;
            const int blL = wl * 2 + bselL;
            const char* hp = hsrc + fl*4096 + blL*16;
            ld16i(qa0, hp);          ld16i(qa1, hp + 1024);
            ld16i(qa2, hp + 2048);   ld16i(qa3, hp + 3072);
        }
        lgkm0_bar();                         // bar2: phase B staged; kh0 exch published

        // ---- H. GEMM phase B (kh==1 waves), K = 256..511, 2-term ----
        if (kh == 1) {
#pragma unroll
            for (int j = 0; j < 8; ++j) {
                const char* bb = ldsst + 32768 + j*4096 + g*1024 + m*16;
                s8v bh0 = *(const s8v*)(bb);
                s8v bh1 = *(const s8v*)(bb + 256);
                s8v bh2 = *(const s8v*)(bb + 512);
                s8v bh3 = *(const s8v*)(bb + 768);
                a0 = __builtin_amdgcn_mfma_f32_16x16x32_bf16(wAh[j], bh0, a0, 0,0,0);
                a1 = __builtin_amdgcn_mfma_f32_16x16x32_bf16(wAh[j], bh1, a1, 0,0,0);
                a2 = __builtin_amdgcn_mfma_f32_16x16x32_bf16(wAh[j], bh2, a2, 0,0,0);
                a3 = __builtin_amdgcn_mfma_f32_16x16x32_bf16(wAh[j], bh3, a3, 0,0,0);
                a0 = __builtin_amdgcn_mfma_f32_16x16x32_bf16(wAl[j], bh0, a0, 0,0,0);
                a1 = __builtin_amdgcn_mfma_f32_16x16x32_bf16(wAl[j], bh1, a1, 0,0,0);
                a2 = __builtin_amdgcn_mfma_f32_16x16x32_bf16(wAl[j], bh2, a2, 0,0,0);
                a3 = __builtin_amdgcn_mfma_f32_16x16x32_bf16(wAl[j], bh3, a3, 0,0,0);
            }
            float* pe = smem + L_EX + ((rb*2 + 1)*64 + lane)*8;
            *(f4v*)(pe)     = a0;
            *(f4v*)(pe + 4) = a1;
        }
        lgkm0_bar();                         // bar3: all exch published

        // ---- I. combine K-halves; cell in registers ----
        {
            const float* px = smem + L_EX + ((rb*2 + (kh^1))*64 + lane)*8;
            f4v r0 = *(const f4v*)(px);
            f4v r1 = *(const f4v*)(px + 4);
            f4v ka, kb;
            if (kh == 0) { ka = a0 + r0; kb = a1 + r1; }
            else         { ka = a2 + r0; kb = a3 + r1; }

            float s00=0,s01=0,s02=0,s03=0, s10=0,s11=0,s12=0,s13=0;
            if (enc) {
                const float* wb2 = smem + L_WIH + (rb*4 + g) * 40;
#pragma unroll
                for (int r2 = 0; r2 < 9; ++r2) {
                    f4v w4 = *(const f4v*)(wb2 + r2*4);
#pragma unroll
                    for (int e = 0; e < 4; ++e) {
                        const int fl2 = r2*4 + e;
                        const int gt = fl2 / 9, d = fl2 - gt*9;
                        const float w = w4[e];
                        const float p0 = xv0[d] * w, p1 = xv1[d] * w;
                        if (gt == 0) { s00 += p0; s10 += p1; }
                        else if (gt == 1) { s01 += p0; s11 += p1; }
                        else if (gt == 2) { s02 += p0; s12 += p1; }
                        else { s03 += p0; s13 += p1; }
                    }
                }
            }
            {
                float vi = ka.x + bias0 + s00, vf = ka.y + bias1 + s01;
                float vg = ka.z + bias2 + s02, vo = ka.w + bias3 + s03;
                float cn = sigmoidf_(vf) * creg0 + sigmoidf_(vi) * tanhf_(vg);
                creg0 = cn;
                smem[L_HNEW + (rb*4 + g) * 65 + c0i] = sigmoidf_(vo) * tanhf_(cn);
            }
            {
                float vi = kb.x + bias0 + s10, vf = kb.y + bias1 + s11;
                float vg = kb.z + bias2 + s12, vo = kb.w + bias3 + s13;
                float cn = sigmoidf_(vf) * creg1 + sigmoidf_(vi) * tanhf_(vg);
                creg1 = cn;
                smem[L_HNEW + (rb*4 + g) * 65 + c0i + 16] = sigmoidf_(vo) * tanhf_(cn);
            }
        }
        lgkm0_bar();                         // bar4: hnew visible

        // ---- J. pack hfrag (hi only) for next step ----
        if (tid < 128) {
            const int col = tid & 63, jblk = (tid >> 6) & 1;
            const int jb = wl * 2 + jblk;
            const int kt = jb >> 2, gg = jb & 3;
            s8v v;
#pragma unroll
            for (int i = 0; i < 8; ++i)
                v[i] = (short)bf16hi_rne(smem[L_HNEW + (jblk * 8 + i) * 65 + col]);
            char* dst = wsb + HFRAG_B + (unsigned)((par^1)*8 + cl)*65536u
                        + (unsigned)(kt*4096 + gg*1024 + col*16);
            *(s8v*)dst = v;
        }
        wait_vm0_mem();   // drains pack stores (qa loads also complete)
        __syncthreads();

        // ---- K. signal ----
        if (tid == 0) {
            if (fast) {
                __hip_atomic_store(flg + wl, (unsigned)(s + 1),
                                   __ATOMIC_RELAXED, __HIP_MEMORY_SCOPE_AGENT);
            } else {
                __builtin_amdgcn_fence(__ATOMIC_RELEASE, "agent");
                __hip_atomic_store(flg + wl, (unsigned)(s + 1),
                                   __ATOMIC_RELEASE, __HIP_MEMORY_SCOPE_AGENT);
            }
        }

        // ---- L. fc compute for h(s) (decode): out[:, s-258, :] ----
        if (dec && fg < 2 * DD) {
            const int bsel = fg / DD, d = fg - bsel * DD;
            const int bl = wl * 2 + bsel;
            const f4v* wf = (const f4v*)(fc_W + d * HH + fl * 32);
            wait_vm0_4i(qa0, qa1, qa2, qa3);   // operand-tied: no hoist past waitcnt
            float acc = 0.f;
            acc += B2F_LO(qa0.x)*wf[0].x + B2F_HI(qa0.x)*wf[0].y
                 + B2F_LO(qa0.y)*wf[0].z + B2F_HI(qa0.y)*wf[0].w
                 + B2F_LO(qa0.z)*wf[1].x + B2F_HI(qa0.z)*wf[1].y
                 + B2F_LO(qa0.w)*wf[1].z + B2F_HI(qa0.w)*wf[1].w;
            acc += B2F_LO(qa1.x)*wf[2].x + B2F_HI(qa1.x)*wf[2].y
                 + B2F_LO(qa1.y)*wf[2].z + B2F_HI(qa1.y)*wf[2].w
                 + B2F_LO(qa1.z)*wf[3].x + B2F_HI(qa1.z)*wf[3].y
                 + B2F_LO(qa1.w)*wf[3].z + B2F_HI(qa1.w)*wf[3].w;
            acc += B2F_LO(qa2.x)*wf[4].x + B2F_HI(qa2.x)*wf[4].y
                 + B2F_LO(qa2.y)*wf[4].z + B2F_HI(qa2.y)*wf[4].w
                 + B2F_LO(qa2.z)*wf[5].x + B2F_HI(qa2.z)*wf[5].y
                 + B2F_LO(qa2.w)*wf[5].z + B2F_HI(qa2.w)*wf[5].w;
            acc += B2F_LO(qa3.x)*wf[6].x + B2F_HI(qa3.x)*wf[6].y
                 + B2F_LO(qa3.y)*wf[6].z + B2F_HI(qa3.y)*wf[6].w
                 + B2F_LO(qa3.z)*wf[7].x + B2F_HI(qa3.z)*wf[7].y
                 + B2F_LO(qa3.w)*wf[7].z + B2F_HI(qa3.w)*wf[7].w;
            acc += __shfl_down(acc, 8, 16);
            acc += __shfl_down(acc, 4, 16);
            acc += __shfl_down(acc, 2, 16);
            acc += __shfl_down(acc, 1, 16);
            if (fl == 0)
                out[(size_t)(nb0 + bl) * (TT * DD) + (s - (TP1 + 1)) * DD + d] =
                    1.0f / (1.0f + __expf(-(acc + fc_b[d])));
        }
    }

    // ---- tail fc: td = 255 from h(513) ----
    {
        if (tid < WPC) {
            for (;;) {
                unsigned v = __hip_atomic_load(flags + cl * 32 + tid,
                                               __ATOMIC_RELAXED, __HIP_MEMORY_SCOPE_AGENT);
                if (__all((int)(v >= (unsigned)NSTEP))) break;
                __builtin_amdgcn_s_sleep(2);
            }
        }
        __syncthreads();
        if (fast) __builtin_amdgcn_fence(__ATOMIC_ACQUIRE, "workgroup");
        else      __builtin_amdgcn_fence(__ATOMIC_ACQUIRE, "agent");

        if (fg < 2 * DD) {
            const int bsel = fg / DD, d = fg - bsel * DD;
            const int bl = wl * 2 + bsel;
            const char* hp = wsb + HFRAG_B + (unsigned)((NSTEP & 1)*8 + cl)*65536u
                             + (unsigned)(fl*4096 + bl*16);
            i4v qa0, qa1, qa2, qa3;
            ld16i(qa0, hp);          ld16i(qa1, hp + 1024);
            ld16i(qa2, hp + 2048);   ld16i(qa3, hp + 3072);
            const f4v* wf = (const f4v*)(fc_W + d * HH + fl * 32);
            wait_vm0_4i(qa0, qa1, qa2, qa3);
            float acc = 0.f;
            acc += B2F_LO(qa0.x)*wf[0].x + B2F_HI(qa0.x)*wf[0].y
                 + B2F_LO(qa0.y)*wf[0].z + B2F_HI(qa0.y)*wf[0].w
                 + B2F_LO(qa0.z)*wf[1].x + B2F_HI(qa0.z)*wf[1].y
                 + B2F_LO(qa0.w)*wf[1].z + B2F_HI(qa0.w)*wf[1].w;
            acc += B2F_LO(qa1.x)*wf[2].x + B2F_HI(qa1.x)*wf[2].y
                 + B2F_LO(qa1.y)*wf[2].z + B2F_HI(qa1.y)*wf[2].w
                 + B2F_LO(qa1.z)*wf[3].x + B2F_HI(qa1.z)*wf[3].y
                 + B2F_LO(qa1.w)*wf[3].z + B2F_HI(qa1.w)*wf[3].w;
            acc += B2F_LO(qa2.x)*wf[4].x + B2F_HI(qa2.x)*wf[4].y
                 + B2F_LO(qa2.y)*wf[4].z + B2F_HI(qa2.y)*wf[4].w
                 + B2F_LO(qa2.z)*wf[5].x + B2F_HI(qa2.z)*wf[5].y
                 + B2F_LO(qa2.w)*wf[5].z + B2F_HI(qa2.w)*wf[5].w;
            acc += B2F_LO(qa3.x)*wf[6].x + B2F_HI(qa3.x)*wf[6].y
                 + B2F_LO(qa3.y)*wf[6].z + B2F_HI(qa3.y)*wf[6].w
                 + B2F_LO(qa3.z)*wf[7].x + B2F_HI(qa3.z)*wf[7].y
                 + B2F_LO(qa3.w)*wf[7].z + B2F_HI(qa3.w)*wf[7].w;
            acc += __shfl_down(acc, 8, 16);
            acc += __shfl_down(acc, 4, 16);
            acc += __shfl_down(acc, 2, 16);
            acc += __shfl_down(acc, 1, 16);
            if (fl == 0)
                out[(size_t)(nb0 + bl) * (TT * DD) + 255 * DD + d] =
                    1.0f / (1.0f + __expf(-(acc + fc_b[d])));
        }
    }
}

extern "C" void kernel_launch(void* const* d_in, const int* in_sizes, int n_in,
                              void* d_out, int out_size, void* d_ws, size_t ws_size,
                              hipStream_t stream) {
    (void)in_sizes; (void)n_in; (void)out_size; (void)ws_size;
    const float* x    = (const float*)d_in[0];
    const float* W_ih = (const float*)d_in[1];
    const float* W_hh = (const float*)d_in[2];
    const float* b_ih = (const float*)d_in[3];
    const float* b_hh = (const float*)d_in[4];
    const float* fc_W = (const float*)d_in[5];
    const float* fc_b = (const float*)d_in[6];
    const float* h0   = (const float*)d_in[7];
    const float* c0   = (const float*)d_in[8];
    float* out = (float*)d_out;
    char*  wsb = (char*)d_ws;

    hipLaunchKernelGGL(rnn_init_kernel, dim3(4096), dim3(256), 0, stream,
                       W_hh, h0, wsb);
    hipLaunchKernelGGL(rnn_persist_kernel, dim3(NWG), dim3(THREADS), 0, stream,
                       x, W_ih, b_ih, b_hh, fc_W, fc_b, c0, wsb, out);
}

// Round 16
// 2298.646 us; speedup vs baseline: 3.5130x; 1.0610x over previous
//
#include <hip/hip_runtime.h>

// N=512 batch, T=256, H=512, D=9. 257 encode + 256 decode steps, LSTM + fc(sigmoid).
// Persistent kernel: 256 wgs x 512 threads (1 wg/CU), 8 clusters x 32 wgs (cl = wg&7 -> one
// XCD). 8 waves = 4 row-tiles x 2 K-halves (W frags 64 VGPR/wave; partials via LDS exchange).
// In-register LSTM cell. amdgpu_waves_per_eu(2,2). 2-term MFMA (W fp32-exact, h bf16).
// R16: un-phased GEMM — one staging pass (one vmcnt(0), one barrier), ALL 8 waves compute
// concurrently; 4 barriers/step (was 5); x prefetched before the flag wait; fc loads in
// flight through the GEMM.

#define TT 256
#define HH 512
#define DD 9
#define TP1 257
#define NSTEP 513
#define THREADS 512
#define NWG 256
#define NCL 8
#define WPC 32

// ws byte offsets
#define WF_HI_B 0u          // Wfrag hi: [wl32][rb4][kt16][lane64][i8] bf16 = 2 MB
#define WF_LO_B 2097152u    // Wfrag lo: 2 MB
#define HFRAG_B 4194304u    // hfrag: [par2][cl8] x 65536 B ([kt16][g4][col64][i8] bf16, hi only)
#define U32_B   8388608u    // flags[256] | ctr @+3072 | xcc @+4096

// LDS float offsets (22164 floats = 86.6 KB; 1 wg/CU)
#define L_ST    0           // staging: 16 kt x 4096 B = 16384 floats
#define L_EX    16384       // acc exchange: 8 slots x 64 lanes x 8 f = 4096 floats
#define L_HNEW  20480       // hnew[u16][65]
#define L_WIH   21520       // wih[u16][40]
#define L_MISC  22160
#define L_TOT   22164

typedef short s8v __attribute__((ext_vector_type(8)));
typedef float f4v __attribute__((ext_vector_type(4)));
typedef int   i4v __attribute__((ext_vector_type(4)));

__device__ __forceinline__ float sigmoidf_(float v){ return 1.0f/(1.0f+__expf(-v)); }
__device__ __forceinline__ float tanhf_(float v){ return 1.0f - 2.0f/(__expf(2.0f*v)+1.0f); }
__device__ __forceinline__ unsigned short bf16hi_rne(float f){
    unsigned u = __float_as_uint(f);
    return (unsigned short)((u + 0x7fffu + ((u>>16)&1u)) >> 16);
}
#define B2F_LO(u) __uint_as_float(((unsigned)(u))<<16)
#define B2F_HI(u) __uint_as_float(((unsigned)(u)) & 0xffff0000u)

__device__ __forceinline__ void ld16i(i4v& d, const char* p){
    asm volatile("global_load_dwordx4 %0, %1, off sc0" : "=v"(d) : "v"(p));
}
__device__ __forceinline__ void wait_vm0_mem(){
    asm volatile("s_waitcnt vmcnt(0)" ::: "memory");
}
__device__ __forceinline__ void wait_vm0_4i(i4v& a0,i4v& a1,i4v& a2,i4v& a3){
    asm volatile("s_waitcnt vmcnt(0)"
                 : "+v"(a0),"+v"(a1),"+v"(a2),"+v"(a3) :: "memory");
}
__device__ __forceinline__ void lgkm0_bar(){
    asm volatile("s_waitcnt lgkmcnt(0)" ::: "memory");
    __builtin_amdgcn_s_barrier();
}

// init: W_hh -> A-frags (hi/lo), tile row = unit*4 + gate; h0 -> hfrag[0] (hi only); zero u32s.
__global__ void rnn_init_kernel(const float* __restrict__ W_hh,
                                const float* __restrict__ h0,
                                char* __restrict__ wsb) {
    int idx = blockIdx.x * blockDim.x + threadIdx.x;   // 0 .. 1048575
    {
        int i  = idx & 7;
        int l  = (idx >> 3) & 63;
        int kt = (idx >> 9) & 15;
        int rb = (idx >> 13) & 3;
        int wl = idx >> 15;
        int mm = l & 15, gg = l >> 4;
        int gt = mm & 3, lu = mm >> 2;               // tile row mm = lu*4 + gt
        int grow = gt * 512 + wl * 16 + rb * 4 + lu;
        int k = kt * 32 + gg * 8 + i;
        float v = W_hh[grow * 512 + k];
        unsigned short hi = bf16hi_rne(v);
        float fh = __uint_as_float(((unsigned)hi) << 16);
        unsigned short lo = bf16hi_rne(v - fh);
        ((unsigned short*)(wsb + WF_HI_B))[idx] = hi;
        ((unsigned short*)(wsb + WF_LO_B))[idx] = lo;
    }
    if (idx < 262144) {   // hfrag par 0: [cl8][kt16][g4][col64][i8], hi only
        int i   = idx & 7;
        int gg  = (idx >> 9) & 3;
        int kt  = (idx >> 11) & 15;
        int cl  = idx >> 15;
        int rem = idx & 32767;
        int j = kt * 32 + gg * 8 + i;
        ((unsigned short*)(wsb + HFRAG_B + (unsigned)cl * 65536u))[rem] = bf16hi_rne(h0[j]);
    }
    if (idx < 2048) ((unsigned int*)(wsb + U32_B))[idx] = 0u;
}

__global__ __attribute__((amdgpu_waves_per_eu(2, 2))) __launch_bounds__(THREADS)
void rnn_persist_kernel(const float* __restrict__ x,
                        const float* __restrict__ W_ih,
                        const float* __restrict__ b_ih,
                        const float* __restrict__ b_hh,
                        const float* __restrict__ fc_W,
                        const float* __restrict__ fc_b,
                        const float* __restrict__ c0,
                        char* __restrict__ wsb,
                        float* __restrict__ out) {
    __shared__ float smem[L_TOT];
    char* ldsst = (char*)smem;          // staging at byte 0 (64 KB)

    const int wg  = blockIdx.x;
    const int cl  = wg & 7;             // cluster -> XCD cl under round-robin
    const int wl  = wg >> 3;            // 0..31
    const int nb0 = cl * 64;
    const int tid = threadIdx.x;
    const int lane = tid & 63;
    const int wid  = tid >> 6;          // 0..7
    const int rb   = wid & 3;           // row-tile (unit block)
    const int kh   = wid >> 2;          // K-half 0/1
    const int m    = lane & 15;
    const int g    = lane >> 4;
    const int gu   = wl * 16 + rb * 4 + g;   // this lane's global hidden unit
    const int c0i  = kh * 32 + m;            // cell col (and +16)

    unsigned int* flags = (unsigned int*)(wsb + U32_B);        // [cl*32 + wl]
    unsigned int* ctr   = (unsigned int*)(wsb + U32_B + 3072);
    unsigned int* xccb  = (unsigned int*)(wsb + U32_B + 4096); // [wg]

    // ---- one-time: wih to LDS ----
    for (int i2 = tid; i2 < 16 * 36; i2 += THREADS) {
        int u = i2 / 36; int r2 = i2 - u * 36; int gt = r2 / 9; int d = r2 - gt * 9;
        smem[L_WIH + u * 40 + gt * 9 + d] = W_ih[(gt * 512 + wl * 16 + u) * DD + d];
    }

    // ---- one-time: per-lane registers: bias (4), c-state (2) ----
    const float bias0 = b_ih[gu]        + b_hh[gu];
    const float bias1 = b_ih[512 + gu]  + b_hh[512 + gu];
    const float bias2 = b_ih[1024 + gu] + b_hh[1024 + gu];
    const float bias3 = b_ih[1536 + gu] + b_hh[1536 + gu];
    float creg0 = c0[gu], creg1 = c0[gu];

    // ---- one-time: W A-frags for THIS wave's K-half (hi + lo): 64 VGPRs ----
    s8v wAh[8], wAl[8];
    {
        const char* base = wsb + (unsigned)(((wl*4 + rb)*16 + kh*8)*64 + lane)*16u;
#pragma unroll
        for (int j = 0; j < 8; ++j) {
            wAh[j] = *(const s8v*)(base + WF_HI_B + j*1024);
            wAl[j] = *(const s8v*)(base + WF_LO_B + j*1024);
        }
    }

    // ---- startup: publish XCD id, grid barrier, co-location check ----
    if (tid == 0) {
        unsigned xcc;
        asm volatile("s_getreg_b32 %0, hwreg(HW_REG_XCC_ID, 0, 32)" : "=s"(xcc));
        __hip_atomic_store(xccb + wg, xcc + 1u, __ATOMIC_RELAXED, __HIP_MEMORY_SCOPE_AGENT);
        __hip_atomic_fetch_add(ctr, 1u, __ATOMIC_RELEASE, __HIP_MEMORY_SCOPE_AGENT);
        while (__hip_atomic_load(ctr, __ATOMIC_RELAXED, __HIP_MEMORY_SCOPE_AGENT) < NWG)
            __builtin_amdgcn_s_sleep(8);
    }
    __syncthreads();
    {
        unsigned v = (tid < WPC)
            ? __hip_atomic_load(xccb + cl + 8 * tid, __ATOMIC_RELAXED,
                                __HIP_MEMORY_SCOPE_AGENT) : 0u;
        unsigned v0 = __shfl(v, 0, 64);
        bool ok = (tid >= WPC) || (v != 0u && v == v0);
        unsigned long long mk = __ballot(ok);
        if (tid == 0) smem[L_MISC] = (mk == ~0ull) ? 1.0f : 0.0f;
    }
    __syncthreads();
    const bool fast = (smem[L_MISC] != 0.0f);

    const int fg = tid >> 4, fl = tid & 15;

    for (int s = 0; s < NSTEP; ++s) {
        const int par = s & 1;
        const char* hsrc = wsb + HFRAG_B + (unsigned)(par*8 + cl) * 65536u;
        unsigned int* flg = flags + cl * 32;
        const bool dec = (s >= TP1 + 1);
        const bool enc = (s < TP1);

        // ---- A0. x prefetch BEFORE the wait (depends only on s) ----
        float xv0[DD], xv1[DD];
        if (enc) {
            const float* xp0 = x + (size_t)(nb0 + c0i) * (TP1 * DD) + s * DD;
            const float* xp1 = x + (size_t)(nb0 + c0i + 16) * (TP1 * DD) + s * DD;
#pragma unroll
            for (int d = 0; d < DD; ++d) { xv0[d] = xp0[d]; xv1[d] = xp1[d]; }
        }

        // ---- A. step wait: per-lane atomic poll ----
        if (s > 0) {
            if (tid < WPC) {
                for (;;) {
                    unsigned v = __hip_atomic_load(flg + tid, __ATOMIC_RELAXED,
                                                   __HIP_MEMORY_SCOPE_AGENT);
                    if (__all((int)(v >= (unsigned)s))) break;
                    __builtin_amdgcn_s_sleep(2);
                }
            }
            __syncthreads();
            if (fast) __builtin_amdgcn_fence(__ATOMIC_ACQUIRE, "workgroup");
            else      __builtin_amdgcn_fence(__ATOMIC_ACQUIRE, "agent");
        }

        // ---- B. issue ALL 16-kt hfrag loads (64 KB; 8 x b128/thread) ----
        i4v hb[8];
#pragma unroll
        for (int c = 0; c < 8; ++c)
            ld16i(hb[c], hsrc + c*8192 + tid*16);

        // ---- D. one vm stall; stage all 16 kt; issue fc loads; one barrier ----
        wait_vm0_mem();
#pragma unroll
        for (int c = 0; c < 8; ++c)
            *(i4v*)(ldsst + c*8192 + tid*16) = hb[c];
        i4v qa0, qa1, qa2, qa3;
        if (dec) {
            const int bselL = (fg < 2 * DD) ? (fg / DD) : 0;
            const int blL = wl * 2 + bselL;
            const char* hp = hsrc + fl*4096 + blL*16;
            ld16i(qa0, hp);          ld16i(qa1, hp + 1024);
            ld16i(qa2, hp + 2048);   ld16i(qa3, hp + 3072);
        }
        lgkm0_bar();                         // bar1: all staged

        // ---- E. GEMM: ALL 8 waves concurrently, each on its K-half, 2-term ----
        f4v a0 = {0,0,0,0}, a1 = {0,0,0,0}, a2 = {0,0,0,0}, a3 = {0,0,0,0};
        {
            const char* base = ldsst + kh*32768;
#pragma unroll
            for (int j = 0; j < 8; ++j) {
                const char* bb = base + j*4096 + g*1024 + m*16;
                s8v bh0 = *(const s8v*)(bb);
                s8v bh1 = *(const s8v*)(bb + 256);
                s8v bh2 = *(const s8v*)(bb + 512);
                s8v bh3 = *(const s8v*)(bb + 768);
                a0 = __builtin_amdgcn_mfma_f32_16x16x32_bf16(wAh[j], bh0, a0, 0,0,0);
                a1 = __builtin_amdgcn_mfma_f32_16x16x32_bf16(wAh[j], bh1, a1, 0,0,0);
                a2 = __builtin_amdgcn_mfma_f32_16x16x32_bf16(wAh[j], bh2, a2, 0,0,0);
                a3 = __builtin_amdgcn_mfma_f32_16x16x32_bf16(wAh[j], bh3, a3, 0,0,0);
                a0 = __builtin_amdgcn_mfma_f32_16x16x32_bf16(wAl[j], bh0, a0, 0,0,0);
                a1 = __builtin_amdgcn_mfma_f32_16x16x32_bf16(wAl[j], bh1, a1, 0,0,0);
                a2 = __builtin_amdgcn_mfma_f32_16x16x32_bf16(wAl[j], bh2, a2, 0,0,0);
                a3 = __builtin_amdgcn_mfma_f32_16x16x32_bf16(wAl[j], bh3, a3, 0,0,0);
            }
            // publish the half this wave does NOT consume:
            // kh0 consumes cols m,m+16 (a0,a1) -> publishes a2,a3 (cols 32..63)
            // kh1 consumes cols 32+m,48+m (a2,a3) -> publishes a0,a1 (cols 0..31)
            float* pe = smem + L_EX + ((rb*2 + kh)*64 + lane)*8;
            if (kh == 0) { *(f4v*)(pe) = a2; *(f4v*)(pe + 4) = a3; }
            else         { *(f4v*)(pe) = a0; *(f4v*)(pe + 4) = a1; }
        }
        lgkm0_bar();                         // bar2: all partials published

        // ---- I. combine K-halves; cell in registers ----
        {
            const float* px = smem + L_EX + ((rb*2 + (kh^1))*64 + lane)*8;
            f4v r0 = *(const f4v*)(px);
            f4v r1 = *(const f4v*)(px + 4);
            f4v ka, kb;
            if (kh == 0) { ka = a0 + r0; kb = a1 + r1; }
            else         { ka = a2 + r0; kb = a3 + r1; }

            float s00=0,s01=0,s02=0,s03=0, s10=0,s11=0,s12=0,s13=0;
            if (enc) {
                const float* wb2 = smem + L_WIH + (rb*4 + g) * 40;
#pragma unroll
                for (int r2 = 0; r2 < 9; ++r2) {
                    f4v w4 = *(const f4v*)(wb2 + r2*4);
#pragma unroll
                    for (int e = 0; e < 4; ++e) {
                        const int fl2 = r2*4 + e;
                        const int gt = fl2 / 9, d = fl2 - gt*9;
                        const float w = w4[e];
                        const float p0 = xv0[d] * w, p1 = xv1[d] * w;
                        if (gt == 0) { s00 += p0; s10 += p1; }
                        else if (gt == 1) { s01 += p0; s11 += p1; }
                        else if (gt == 2) { s02 += p0; s12 += p1; }
                        else { s03 += p0; s13 += p1; }
                    }
                }
            }
            {
                float vi = ka.x + bias0 + s00, vf = ka.y + bias1 + s01;
                float vg = ka.z + bias2 + s02, vo = ka.w + bias3 + s03;
                float cn = sigmoidf_(vf) * creg0 + sigmoidf_(vi) * tanhf_(vg);
                creg0 = cn;
                smem[L_HNEW + (rb*4 + g) * 65 + c0i] = sigmoidf_(vo) * tanhf_(cn);
            }
            {
                float vi = kb.x + bias0 + s10, vf = kb.y + bias1 + s11;
                float vg = kb.z + bias2 + s12, vo = kb.w + bias3 + s13;
                float cn = sigmoidf_(vf) * creg1 + sigmoidf_(vi) * tanhf_(vg);
                creg1 = cn;
                smem[L_HNEW + (rb*4 + g) * 65 + c0i + 16] = sigmoidf_(vo) * tanhf_(cn);
            }
        }
        lgkm0_bar();                         // bar3: hnew visible

        // ---- J. pack hfrag (hi only) for next step ----
        if (tid < 128) {
            const int col = tid & 63, jblk = (tid >> 6) & 1;
            const int jb = wl * 2 + jblk;
            const int kt = jb >> 2, gg = jb & 3;
            s8v v;
#pragma unroll
            for (int i = 0; i < 8; ++i)
                v[i] = (short)bf16hi_rne(smem[L_HNEW + (jblk * 8 + i) * 65 + col]);
            char* dst = wsb + HFRAG_B + (unsigned)((par^1)*8 + cl)*65536u
                        + (unsigned)(kt*4096 + gg*1024 + col*16);
            *(s8v*)dst = v;
        }
        wait_vm0_mem();   // drains pack stores (qa loads also complete)
        __syncthreads();                     // bar4: all pack stores drained

        // ---- K. signal ----
        if (tid == 0) {
            if (fast) {
                __hip_atomic_store(flg + wl, (unsigned)(s + 1),
                                   __ATOMIC_RELAXED, __HIP_MEMORY_SCOPE_AGENT);
            } else {
                __builtin_amdgcn_fence(__ATOMIC_RELEASE, "agent");
                __hip_atomic_store(flg + wl, (unsigned)(s + 1),
                                   __ATOMIC_RELEASE, __HIP_MEMORY_SCOPE_AGENT);
            }
        }

        // ---- L. fc compute for h(s) (decode): out[:, s-258, :] ----
        if (dec && fg < 2 * DD) {
            const int bsel = fg / DD, d = fg - bsel * DD;
            const int bl = wl * 2 + bsel;
            const f4v* wf = (const f4v*)(fc_W + d * HH + fl * 32);
            wait_vm0_4i(qa0, qa1, qa2, qa3);   // operand-tied: no hoist past waitcnt
            float acc = 0.f;
            acc += B2F_LO(qa0.x)*wf[0].x + B2F_HI(qa0.x)*wf[0].y
                 + B2F_LO(qa0.y)*wf[0].z + B2F_HI(qa0.y)*wf[0].w
                 + B2F_LO(qa0.z)*wf[1].x + B2F_HI(qa0.z)*wf[1].y
                 + B2F_LO(qa0.w)*wf[1].z + B2F_HI(qa0.w)*wf[1].w;
            acc += B2F_LO(qa1.x)*wf[2].x + B2F_HI(qa1.x)*wf[2].y
                 + B2F_LO(qa1.y)*wf[2].z + B2F_HI(qa1.y)*wf[2].w
                 + B2F_LO(qa1.z)*wf[3].x + B2F_HI(qa1.z)*wf[3].y
                 + B2F_LO(qa1.w)*wf[3].z + B2F_HI(qa1.w)*wf[3].w;
            acc += B2F_LO(qa2.x)*wf[4].x + B2F_HI(qa2.x)*wf[4].y
                 + B2F_LO(qa2.y)*wf[4].z + B2F_HI(qa2.y)*wf[4].w
                 + B2F_LO(qa2.z)*wf[5].x + B2F_HI(qa2.z)*wf[5].y
                 + B2F_LO(qa2.w)*wf[5].z + B2F_HI(qa2.w)*wf[5].w;
            acc += B2F_LO(qa3.x)*wf[6].x + B2F_HI(qa3.x)*wf[6].y
                 + B2F_LO(qa3.y)*wf[6].z + B2F_HI(qa3.y)*wf[6].w
                 + B2F_LO(qa3.z)*wf[7].x + B2F_HI(qa3.z)*wf[7].y
                 + B2F_LO(qa3.w)*wf[7].z + B2F_HI(qa3.w)*wf[7].w;
            acc += __shfl_down(acc, 8, 16);
            acc += __shfl_down(acc, 4, 16);
            acc += __shfl_down(acc, 2, 16);
            acc += __shfl_down(acc, 1, 16);
            if (fl == 0)
                out[(size_t)(nb0 + bl) * (TT * DD) + (s - (TP1 + 1)) * DD + d] =
                    1.0f / (1.0f + __expf(-(acc + fc_b[d])));
        }
    }

    // ---- tail fc: td = 255 from h(513) ----
    {
        if (tid < WPC) {
            for (;;) {
                unsigned v = __hip_atomic_load(flags + cl * 32 + tid,
                                               __ATOMIC_RELAXED, __HIP_MEMORY_SCOPE_AGENT);
                if (__all((int)(v >= (unsigned)NSTEP))) break;
                __builtin_amdgcn_s_sleep(2);
            }
        }
        __syncthreads();
        if (fast) __builtin_amdgcn_fence(__ATOMIC_ACQUIRE, "workgroup");
        else      __builtin_amdgcn_fence(__ATOMIC_ACQUIRE, "agent");

        if (fg < 2 * DD) {
            const int bsel = fg / DD, d = fg - bsel * DD;
            const int bl = wl * 2 + bsel;
            const char* hp = wsb + HFRAG_B + (unsigned)((NSTEP & 1)*8 + cl)*65536u
                             + (unsigned)(fl*4096 + bl*16);
            i4v qa0, qa1, qa2, qa3;
            ld16i(qa0, hp);          ld16i(qa1, hp + 1024);
            ld16i(qa2, hp + 2048);   ld16i(qa3, hp + 3072);
            const f4v* wf = (const f4v*)(fc_W + d * HH + fl * 32);
            wait_vm0_4i(qa0, qa1, qa2, qa3);
            float acc = 0.f;
            acc += B2F_LO(qa0.x)*wf[0].x + B2F_HI(qa0.x)*wf[0].y
                 + B2F_LO(qa0.y)*wf[0].z + B2F_HI(qa0.y)*wf[0].w
                 + B2F_LO(qa0.z)*wf[1].x + B2F_HI(qa0.z)*wf[1].y
                 + B2F_LO(qa0.w)*wf[1].z + B2F_HI(qa0.w)*wf[1].w;
            acc += B2F_LO(qa1.x)*wf[2].x + B2F_HI(qa1.x)*wf[2].y
                 + B2F_LO(qa1.y)*wf[2].z + B2F_HI(qa1.y)*wf[2].w
                 + B2F_LO(qa1.z)*wf[3].x + B2F_HI(qa1.z)*wf[3].y
                 + B2F_LO(qa1.w)*wf[3].z + B2F_HI(qa1.w)*wf[3].w;
            acc += B2F_LO(qa2.x)*wf[4].x + B2F_HI(qa2.x)*wf[4].y
                 + B2F_LO(qa2.y)*wf[4].z + B2F_HI(qa2.y)*wf[4].w
                 + B2F_LO(qa2.z)*wf[5].x + B2F_HI(qa2.z)*wf[5].y
                 + B2F_LO(qa2.w)*wf[5].z + B2F_HI(qa2.w)*wf[5].w;
            acc += B2F_LO(qa3.x)*wf[6].x + B2F_HI(qa3.x)*wf[6].y
                 + B2F_LO(qa3.y)*wf[6].z + B2F_HI(qa3.y)*wf[6].w
                 + B2F_LO(qa3.z)*wf[7].x + B2F_HI(qa3.z)*wf[7].y
                 + B2F_LO(qa3.w)*wf[7].z + B2F_HI(qa3.w)*wf[7].w;
            acc += __shfl_down(acc, 8, 16);
            acc += __shfl_down(acc, 4, 16);
            acc += __shfl_down(acc, 2, 16);
            acc += __shfl_down(acc, 1, 16);
            if (fl == 0)
                out[(size_t)(nb0 + bl) * (TT * DD) + 255 * DD + d] =
                    1.0f / (1.0f + __expf(-(acc + fc_b[d])));
        }
    }
}

extern "C" void kernel_launch(void* const* d_in, const int* in_sizes, int n_in,
                              void* d_out, int out_size, void* d_ws, size_t ws_size,
                              hipStream_t stream) {
    (void)in_sizes; (void)n_in; (void)out_size; (void)ws_size;
    const float* x    = (const float*)d_in[0];
    const float* W_ih = (const float*)d_in[1];
    const float* W_hh = (const float*)d_in[2];
    const float* b_ih = (const float*)d_in[3];
    const float* b_hh = (const float*)d_in[4];
    const float* fc_W = (const float*)d_in[5];
    const float* fc_b = (const float*)d_in[6];
    const float* h0   = (const float*)d_in[7];
    const float* c0   = (const float*)d_in[8];
    float* out = (float*)d_out;
    char*  wsb = (char*)d_ws;

    hipLaunchKernelGGL(rnn_init_kernel, dim3(4096), dim3(256), 0, stream,
                       W_hh, h0, wsb);
    hipLaunchKernelGGL(rnn_persist_kernel, dim3(NWG), dim3(THREADS), 0, stream,
                       x, W_ih, b_ih, b_hh, fc_W, fc_b, c0, wsb, out);
}

// Round 17
// 2102.341 us; speedup vs baseline: 3.8410x; 1.0934x over previous
//
#include <hip/hip_runtime.h>

// N=512 batch, T=256, H=512, D=9. 257 encode + 256 decode steps, LSTM + fc(sigmoid).
// Persistent kernel: 256 wgs x 512 threads (1 wg/CU), 16 clusters x 16 wgs (cl = wg&15 ->
// one XCD since 16%8==0; runtime-verified). wg owns 32 hidden units, ALL of K (no K-split,
// no partial exchange): 8 waves = 8 unit-blocks of 4. W frags 128 VGPR/lane (2-term: W
// fp32-exact via hi+lo, h bf16). In-register LSTM cell. amdgpu_waves_per_eu(2,2).
// R17: consensus set halved (16 wgs), exchange barrier deleted, staging halved (32 KB).

#define TT 256
#define HH 512
#define DD 9
#define TP1 257
#define NSTEP 513
#define THREADS 512
#define NWG 256
#define NCL 16
#define WPC 16

// ws byte offsets
#define WF_HI_B 0u          // Wfrag hi: [wl16][rb8][kt16][lane64][i8] bf16 = 2 MB
#define WF_LO_B 2097152u    // Wfrag lo: 2 MB
#define HFRAG_B 4194304u    // hfrag: [par2][cl16] x 32768 B ([kt16][g4][col32][i8] bf16)
#define U32_B   8388608u    // flags[256] | ctr @+3072 | xcc @+4096

// LDS float offsets (10532 floats = 41.1 KB; 1 wg/CU)
#define L_ST    0           // staging: 16 kt x 2048 B = 8192 floats
#define L_HNEW  8192        // hnew[u32][33]
#define L_WIH   9248        // wih[u32][40]
#define L_MISC  10528
#define L_TOT   10532

typedef short s8v __attribute__((ext_vector_type(8)));
typedef float f4v __attribute__((ext_vector_type(4)));
typedef int   i4v __attribute__((ext_vector_type(4)));

__device__ __forceinline__ float sigmoidf_(float v){ return 1.0f/(1.0f+__expf(-v)); }
__device__ __forceinline__ float tanhf_(float v){ return 1.0f - 2.0f/(__expf(2.0f*v)+1.0f); }
__device__ __forceinline__ unsigned short bf16hi_rne(float f){
    unsigned u = __float_as_uint(f);
    return (unsigned short)((u + 0x7fffu + ((u>>16)&1u)) >> 16);
}
#define B2F_LO(u) __uint_as_float(((unsigned)(u))<<16)
#define B2F_HI(u) __uint_as_float(((unsigned)(u)) & 0xffff0000u)

__device__ __forceinline__ void ld16i(i4v& d, const char* p){
    asm volatile("global_load_dwordx4 %0, %1, off sc0" : "=v"(d) : "v"(p));
}
__device__ __forceinline__ void wait_vm0_mem(){
    asm volatile("s_waitcnt vmcnt(0)" ::: "memory");
}
__device__ __forceinline__ void wait_vm0_4i(i4v& a0,i4v& a1,i4v& a2,i4v& a3){
    asm volatile("s_waitcnt vmcnt(0)"
                 : "+v"(a0),"+v"(a1),"+v"(a2),"+v"(a3) :: "memory");
}
__device__ __forceinline__ void lgkm0_bar(){
    asm volatile("s_waitcnt lgkmcnt(0)" ::: "memory");
    __builtin_amdgcn_s_barrier();
}

// init: W_hh -> A-frags (hi/lo), [wl16][rb8][kt16][lane][i]; tile row = lu*4+gt with
// unit = wl*32 + rb*4 + lu. h0 -> hfrag[0]. zero u32s.
__global__ void rnn_init_kernel(const float* __restrict__ W_hh,
                                const float* __restrict__ h0,
                                char* __restrict__ wsb) {
    int idx = blockIdx.x * blockDim.x + threadIdx.x;   // 0 .. 1048575
    {
        int i    = idx & 7;
        int lane = (idx >> 3) & 63;
        int kt   = (idx >> 9) & 15;
        int rb   = (idx >> 13) & 7;
        int wl   = idx >> 16;
        int mm = lane & 15, g = lane >> 4;
        int gt = mm & 3, lu = mm >> 2;               // tile row mm = lu*4 + gt
        int grow = gt * 512 + wl * 32 + rb * 4 + lu;
        int k = kt * 32 + g * 8 + i;
        float v = W_hh[grow * 512 + k];
        unsigned short hi = bf16hi_rne(v);
        float fh = __uint_as_float(((unsigned)hi) << 16);
        unsigned short lo = bf16hi_rne(v - fh);
        ((unsigned short*)(wsb + WF_HI_B))[idx] = hi;
        ((unsigned short*)(wsb + WF_LO_B))[idx] = lo;
    }
    if (idx < 262144) {   // hfrag par 0: [cl16][kt16][g4][col32][i8]
        int i   = idx & 7;
        int gg  = (idx >> 8) & 3;
        int kt  = (idx >> 10) & 15;
        int cl  = idx >> 14;
        int rem = idx & 16383;
        int j = kt * 32 + gg * 8 + i;
        ((unsigned short*)(wsb + HFRAG_B + (unsigned)cl * 32768u))[rem] = bf16hi_rne(h0[j]);
    }
    if (idx < 2048) ((unsigned int*)(wsb + U32_B))[idx] = 0u;
}

__global__ __attribute__((amdgpu_waves_per_eu(2, 2))) __launch_bounds__(THREADS)
void rnn_persist_kernel(const float* __restrict__ x,
                        const float* __restrict__ W_ih,
                        const float* __restrict__ b_ih,
                        const float* __restrict__ b_hh,
                        const float* __restrict__ fc_W,
                        const float* __restrict__ fc_b,
                        const float* __restrict__ c0,
                        char* __restrict__ wsb,
                        float* __restrict__ out) {
    __shared__ float smem[L_TOT];
    char* ldsst = (char*)smem;          // staging at byte 0 (32 KB)

    const int wg  = blockIdx.x;
    const int cl  = wg & 15;            // cluster; XCD = cl&7 (16%8==0 keeps it pure)
    const int wl  = wg >> 4;            // 0..15
    const int nb0 = cl * 32;
    const int tid = threadIdx.x;
    const int lane = tid & 63;
    const int rb   = tid >> 6;          // wave id = unit block rb*4..rb*4+3 (0..7)
    const int m    = lane & 15;
    const int g    = lane >> 4;
    const int gu   = wl * 32 + rb * 4 + g;   // this lane's global hidden unit
    const int uu   = rb * 4 + g;             // local unit (0..31)

    unsigned int* flags = (unsigned int*)(wsb + U32_B);        // [cl*16 + wl]
    unsigned int* ctr   = (unsigned int*)(wsb + U32_B + 3072);
    unsigned int* xccb  = (unsigned int*)(wsb + U32_B + 4096); // [wg]

    // ---- one-time: wih to LDS (32 local units x 4 gates x 9) ----
    for (int i2 = tid; i2 < 32 * 36; i2 += THREADS) {
        int u = i2 / 36; int r2 = i2 - u * 36; int gt = r2 / 9; int d = r2 - gt * 9;
        smem[L_WIH + u * 40 + gt * 9 + d] = W_ih[(gt * 512 + wl * 32 + u) * DD + d];
    }

    // ---- one-time: per-lane registers: bias (4), c-state (2) ----
    const float bias0 = b_ih[gu]        + b_hh[gu];
    const float bias1 = b_ih[512 + gu]  + b_hh[512 + gu];
    const float bias2 = b_ih[1024 + gu] + b_hh[1024 + gu];
    const float bias3 = b_ih[1536 + gu] + b_hh[1536 + gu];
    float creg0 = c0[gu], creg1 = c0[gu];

    // ---- one-time: W A-frags, FULL K (hi + lo): 128 VGPRs ----
    s8v wAh[16], wAl[16];
    {
        const char* base = wsb + (unsigned)(((wl*8 + rb)*16)*64 + lane)*16u;
#pragma unroll
        for (int j = 0; j < 16; ++j) {
            wAh[j] = *(const s8v*)(base + WF_HI_B + j*1024);
            wAl[j] = *(const s8v*)(base + WF_LO_B + j*1024);
        }
    }

    // ---- startup: publish XCD id, grid barrier, co-location check ----
    if (tid == 0) {
        unsigned xcc;
        asm volatile("s_getreg_b32 %0, hwreg(HW_REG_XCC_ID, 0, 32)" : "=s"(xcc));
        __hip_atomic_store(xccb + wg, xcc + 1u, __ATOMIC_RELAXED, __HIP_MEMORY_SCOPE_AGENT);
        __hip_atomic_fetch_add(ctr, 1u, __ATOMIC_RELEASE, __HIP_MEMORY_SCOPE_AGENT);
        while (__hip_atomic_load(ctr, __ATOMIC_RELAXED, __HIP_MEMORY_SCOPE_AGENT) < NWG)
            __builtin_amdgcn_s_sleep(8);
    }
    __syncthreads();
    {
        unsigned v = (tid < WPC)
            ? __hip_atomic_load(xccb + cl + 16 * tid, __ATOMIC_RELAXED,
                                __HIP_MEMORY_SCOPE_AGENT) : 0u;
        unsigned v0 = __shfl(v, 0, 64);
        bool ok = (tid >= WPC) || (v != 0u && v == v0);
        unsigned long long mk = __ballot(ok);
        if (tid == 0) smem[L_MISC] = (mk == ~0ull) ? 1.0f : 0.0f;
    }
    __syncthreads();
    const bool fast = (smem[L_MISC] != 0.0f);

    const int fg = tid >> 4, fl = tid & 15;

    for (int s = 0; s < NSTEP; ++s) {
        const int par = s & 1;
        const char* hsrc = wsb + HFRAG_B + (unsigned)(par*16 + cl) * 32768u;
        unsigned int* flg = flags + cl * 16;
        const bool dec = (s >= TP1 + 1);
        const bool enc = (s < TP1);

        // ---- A0. x prefetch BEFORE the wait ----
        float xv0[DD], xv1[DD];
        if (enc) {
            const float* xp0 = x + (size_t)(nb0 + m) * (TP1 * DD) + s * DD;
            const float* xp1 = x + (size_t)(nb0 + m + 16) * (TP1 * DD) + s * DD;
#pragma unroll
            for (int d = 0; d < DD; ++d) { xv0[d] = xp0[d]; xv1[d] = xp1[d]; }
        }

        // ---- A. step wait: 16 producer flags ----
        if (s > 0) {
            if (tid < WPC) {
                for (;;) {
                    unsigned v = __hip_atomic_load(flg + tid, __ATOMIC_RELAXED,
                                                   __HIP_MEMORY_SCOPE_AGENT);
                    if (__all((int)(v >= (unsigned)s))) break;
                    __builtin_amdgcn_s_sleep(2);
                }
            }
            __syncthreads();
            if (fast) __builtin_amdgcn_fence(__ATOMIC_ACQUIRE, "workgroup");
            else      __builtin_amdgcn_fence(__ATOMIC_ACQUIRE, "agent");
        }

        // ---- B. issue all hfrag loads (32 KB; 4 x b128/thread) ----
        i4v hb[4];
#pragma unroll
        for (int c = 0; c < 4; ++c)
            ld16i(hb[c], hsrc + c*8192 + tid*16);

        // ---- D. one vm stall; stage; issue fc loads; one barrier ----
        wait_vm0_mem();
#pragma unroll
        for (int c = 0; c < 4; ++c)
            *(i4v*)(ldsst + c*8192 + tid*16) = hb[c];
        i4v qa0, qa1, qa2, qa3;
        if (dec) {
            const int bselL = (fg < 2 * DD) ? (fg / DD) : 0;
            const int blL = wl * 2 + bselL;
            const char* hp = hsrc + fl*2048 + blL*16;
            ld16i(qa0, hp);          ld16i(qa1, hp + 512);
            ld16i(qa2, hp + 1024);   ld16i(qa3, hp + 1536);
        }
        lgkm0_bar();                         // bar1: all staged

        // ---- E. GEMM: all 8 waves, full K=512, 2-term, 2 col-tiles ----
        f4v a0 = {0,0,0,0}, a1 = {0,0,0,0};
#pragma unroll
        for (int j = 0; j < 16; ++j) {
            const char* bb = ldsst + j*2048 + g*512 + m*16;
            s8v bh0 = *(const s8v*)(bb);          // cols 0..15 (col m)
            s8v bh1 = *(const s8v*)(bb + 256);    // cols 16..31 (col m+16)
            a0 = __builtin_amdgcn_mfma_f32_16x16x32_bf16(wAh[j], bh0, a0, 0,0,0);
            a1 = __builtin_amdgcn_mfma_f32_16x16x32_bf16(wAh[j], bh1, a1, 0,0,0);
            a0 = __builtin_amdgcn_mfma_f32_16x16x32_bf16(wAl[j], bh0, a0, 0,0,0);
            a1 = __builtin_amdgcn_mfma_f32_16x16x32_bf16(wAl[j], bh1, a1, 0,0,0);
        }

        // ---- I. cell in registers (no exchange needed) ----
        {
            float s00=0,s01=0,s02=0,s03=0, s10=0,s11=0,s12=0,s13=0;
            if (enc) {
                const float* wb2 = smem + L_WIH + uu * 40;
#pragma unroll
                for (int r2 = 0; r2 < 9; ++r2) {
                    f4v w4 = *(const f4v*)(wb2 + r2*4);
#pragma unroll
                    for (int e = 0; e < 4; ++e) {
                        const int fl2 = r2*4 + e;
                        const int gt = fl2 / 9, d = fl2 - gt*9;
                        const float w = w4[e];
                        const float p0 = xv0[d] * w, p1 = xv1[d] * w;
                        if (gt == 0) { s00 += p0; s10 += p1; }
                        else if (gt == 1) { s01 += p0; s11 += p1; }
                        else if (gt == 2) { s02 += p0; s12 += p1; }
                        else { s03 += p0; s13 += p1; }
                    }
                }
            }
            {
                float vi = a0.x + bias0 + s00, vf = a0.y + bias1 + s01;
                float vg = a0.z + bias2 + s02, vo = a0.w + bias3 + s03;
                float cn = sigmoidf_(vf) * creg0 + sigmoidf_(vi) * tanhf_(vg);
                creg0 = cn;
                smem[L_HNEW + uu * 33 + m] = sigmoidf_(vo) * tanhf_(cn);
            }
            {
                float vi = a1.x + bias0 + s10, vf = a1.y + bias1 + s11;
                float vg = a1.z + bias2 + s12, vo = a1.w + bias3 + s13;
                float cn = sigmoidf_(vf) * creg1 + sigmoidf_(vi) * tanhf_(vg);
                creg1 = cn;
                smem[L_HNEW + uu * 33 + m + 16] = sigmoidf_(vo) * tanhf_(cn);
            }
        }
        lgkm0_bar();                         // bar2: hnew visible

        // ---- J. pack hfrag for next step: this wg owns kt = wl slot (2 KB) ----
        if (tid < 128) {
            const int col = tid & 31, gg = tid >> 5;   // gg 0..3
            s8v v;
#pragma unroll
            for (int i = 0; i < 8; ++i)
                v[i] = (short)bf16hi_rne(smem[L_HNEW + (gg * 8 + i) * 33 + col]);
            char* dst = wsb + HFRAG_B + (unsigned)((par^1)*16 + cl)*32768u
                        + (unsigned)(wl*2048 + gg*512 + col*16);
            *(s8v*)dst = v;
        }
        wait_vm0_mem();   // drains pack stores (qa loads also complete)
        __syncthreads();                     // bar3

        // ---- K. signal ----
        if (tid == 0) {
            if (fast) {
                __hip_atomic_store(flg + wl, (unsigned)(s + 1),
                                   __ATOMIC_RELAXED, __HIP_MEMORY_SCOPE_AGENT);
            } else {
                __builtin_amdgcn_fence(__ATOMIC_RELEASE, "agent");
                __hip_atomic_store(flg + wl, (unsigned)(s + 1),
                                   __ATOMIC_RELEASE, __HIP_MEMORY_SCOPE_AGENT);
            }
        }

        // ---- L. fc compute for h(s) (decode): out[:, s-258, :] ----
        if (dec && fg < 2 * DD) {
            const int bsel = fg / DD, d = fg - bsel * DD;
            const int bl = wl * 2 + bsel;
            const f4v* wf = (const f4v*)(fc_W + d * HH + fl * 32);
            wait_vm0_4i(qa0, qa1, qa2, qa3);   // operand-tied: no hoist past waitcnt
            float acc = 0.f;
            acc += B2F_LO(qa0.x)*wf[0].x + B2F_HI(qa0.x)*wf[0].y
                 + B2F_LO(qa0.y)*wf[0].z + B2F_HI(qa0.y)*wf[0].w
                 + B2F_LO(qa0.z)*wf[1].x + B2F_HI(qa0.z)*wf[1].y
                 + B2F_LO(qa0.w)*wf[1].z + B2F_HI(qa0.w)*wf[1].w;
            acc += B2F_LO(qa1.x)*wf[2].x + B2F_HI(qa1.x)*wf[2].y
                 + B2F_LO(qa1.y)*wf[2].z + B2F_HI(qa1.y)*wf[2].w
                 + B2F_LO(qa1.z)*wf[3].x + B2F_HI(qa1.z)*wf[3].y
                 + B2F_LO(qa1.w)*wf[3].z + B2F_HI(qa1.w)*wf[3].w;
            acc += B2F_LO(qa2.x)*wf[4].x + B2F_HI(qa2.x)*wf[4].y
                 + B2F_LO(qa2.y)*wf[4].z + B2F_HI(qa2.y)*wf[4].w
                 + B2F_LO(qa2.z)*wf[5].x + B2F_HI(qa2.z)*wf[5].y
                 + B2F_LO(qa2.w)*wf[5].z + B2F_HI(qa2.w)*wf[5].w;
            acc += B2F_LO(qa3.x)*wf[6].x + B2F_HI(qa3.x)*wf[6].y
                 + B2F_LO(qa3.y)*wf[6].z + B2F_HI(qa3.y)*wf[6].w
                 + B2F_LO(qa3.z)*wf[7].x + B2F_HI(qa3.z)*wf[7].y
                 + B2F_LO(qa3.w)*wf[7].z + B2F_HI(qa3.w)*wf[7].w;
            acc += __shfl_down(acc, 8, 16);
            acc += __shfl_down(acc, 4, 16);
            acc += __shfl_down(acc, 2, 16);
            acc += __shfl_down(acc, 1, 16);
            if (fl == 0)
                out[(size_t)(nb0 + bl) * (TT * DD) + (s - (TP1 + 1)) * DD + d] =
                    1.0f / (1.0f + __expf(-(acc + fc_b[d])));
        }
    }

    // ---- tail fc: td = 255 from h(513) ----
    {
        if (tid < WPC) {
            for (;;) {
                unsigned v = __hip_atomic_load(flags + cl * 16 + tid,
                                               __ATOMIC_RELAXED, __HIP_MEMORY_SCOPE_AGENT);
                if (__all((int)(v >= (unsigned)NSTEP))) break;
                __builtin_amdgcn_s_sleep(2);
            }
        }
        __syncthreads();
        if (fast) __builtin_amdgcn_fence(__ATOMIC_ACQUIRE, "workgroup");
        else      __builtin_amdgcn_fence(__ATOMIC_ACQUIRE, "agent");

        if (fg < 2 * DD) {
            const int bsel = fg / DD, d = fg - bsel * DD;
            const int bl = wl * 2 + bsel;
            const char* hp = wsb + HFRAG_B + (unsigned)((NSTEP & 1)*16 + cl)*32768u
                             + (unsigned)(fl*2048 + bl*16);
            i4v qa0, qa1, qa2, qa3;
            ld16i(qa0, hp);          ld16i(qa1, hp + 512);
            ld16i(qa2, hp + 1024);   ld16i(qa3, hp + 1536);
            const f4v* wf = (const f4v*)(fc_W + d * HH + fl * 32);
            wait_vm0_4i(qa0, qa1, qa2, qa3);
            float acc = 0.f;
            acc += B2F_LO(qa0.x)*wf[0].x + B2F_HI(qa0.x)*wf[0].y
                 + B2F_LO(qa0.y)*wf[0].z + B2F_HI(qa0.y)*wf[0].w
                 + B2F_LO(qa0.z)*wf[1].x + B2F_HI(qa0.z)*wf[1].y
                 + B2F_LO(qa0.w)*wf[1].z + B2F_HI(qa0.w)*wf[1].w;
            acc += B2F_LO(qa1.x)*wf[2].x + B2F_HI(qa1.x)*wf[2].y
                 + B2F_LO(qa1.y)*wf[2].z + B2F_HI(qa1.y)*wf[2].w
                 + B2F_LO(qa1.z)*wf[3].x + B2F_HI(qa1.z)*wf[3].y
                 + B2F_LO(qa1.w)*wf[3].z + B2F_HI(qa1.w)*wf[3].w;
            acc += B2F_LO(qa2.x)*wf[4].x + B2F_HI(qa2.x)*wf[4].y
                 + B2F_LO(qa2.y)*wf[4].z + B2F_HI(qa2.y)*wf[4].w
                 + B2F_LO(qa2.z)*wf[5].x + B2F_HI(qa2.z)*wf[5].y
                 + B2F_LO(qa2.w)*wf[5].z + B2F_HI(qa2.w)*wf[5].w;
            acc += B2F_LO(qa3.x)*wf[6].x + B2F_HI(qa3.x)*wf[6].y
                 + B2F_LO(qa3.y)*wf[6].z + B2F_HI(qa3.y)*wf[6].w
                 + B2F_LO(qa3.z)*wf[7].x + B2F_HI(qa3.z)*wf[7].y
                 + B2F_LO(qa3.w)*wf[7].z + B2F_HI(qa3.w)*wf[7].w;
            acc += __shfl_down(acc, 8, 16);
            acc += __shfl_down(acc, 4, 16);
            acc += __shfl_down(acc, 2, 16);
            acc += __shfl_down(acc, 1, 16);
            if (fl == 0)
                out[(size_t)(nb0 + bl) * (TT * DD) + 255 * DD + d] =
                    1.0f / (1.0f + __expf(-(acc + fc_b[d])));
        }
    }
}

extern "C" void kernel_launch(void* const* d_in, const int* in_sizes, int n_in,
                              void* d_out, int out_size, void* d_ws, size_t ws_size,
                              hipStream_t stream) {
    (void)in_sizes; (void)n_in; (void)out_size; (void)ws_size;
    const float* x    = (const float*)d_in[0];
    const float* W_ih = (const float*)d_in[1];
    const float* W_hh = (const float*)d_in[2];
    const float* b_ih = (const float*)d_in[3];
    const float* b_hh = (const float*)d_in[4];
    const float* fc_W = (const float*)d_in[5];
    const float* fc_b = (const float*)d_in[6];
    const float* h0   = (const float*)d_in[7];
    const float* c0   = (const float*)d_in[8];
    float* out = (float*)d_out;
    char*  wsb = (char*)d_ws;

    hipLaunchKernelGGL(rnn_init_kernel, dim3(4096), dim3(256), 0, stream,
                       W_hh, h0, wsb);
    hipLaunchKernelGGL(rnn_persist_kernel, dim3(NWG), dim3(THREADS), 0, stream,
                       x, W_ih, b_ih, b_hh, fc_W, fc_b, c0, wsb, out);
}